// Round 1
// baseline (3253.698 us; speedup 1.0000x reference)
//
#include <hip/hip_runtime.h>

// Problem constants
#define Bn   8
#define Sn   1024
#define Dn   1024
#define Rn   256
#define NHn  16
#define DHn  64
#define NKn  4096
#define TOK  (Bn*Sn)        // 8192 tokens
#define EPE  (Dn*Rn)        // 262144 elements per expert table entry

// ======================================================================
// Router: per token, logits for 5 routers (64 experts each), softmax,
// multiply by importance, write pref[r][tok][64].
// ======================================================================
__global__ __launch_bounds__(256) void router_kernel(
    const float* __restrict__ x, const float* __restrict__ imp,
    const float* __restrict__ w0, const float* __restrict__ w1,
    const float* __restrict__ w2, const float* __restrict__ w3,
    const float* __restrict__ w4, float* __restrict__ pref)
{
    int bs  = blockIdx.x;          // token 0..8191
    int tid = threadIdx.x;
    __shared__ __align__(16) float xs[Dn];
    __shared__ float lg[64];
    for (int i = tid; i < Dn; i += 256) xs[i] = x[(size_t)bs*Dn + i];
    float im = imp[bs];
    int n = tid >> 2, q = tid & 3;           // 4 lanes per expert logit
    const float* ws[5] = {w0, w1, w2, w3, w4};
#pragma unroll
    for (int rr = 0; rr < 5; ++rr) {
        __syncthreads();
        const float* w = ws[rr] + (size_t)n*Dn;
        float acc = 0.f;
#pragma unroll 4
        for (int j = 0; j < 64; ++j) {
            int i4 = (j*4 + q)*4;
            float4 xv = *(const float4*)&xs[i4];
            float4 wv = *(const float4*)&w[i4];
            acc += xv.x*wv.x + xv.y*wv.y + xv.z*wv.z + xv.w*wv.w;
        }
        acc += __shfl_xor(acc, 1);
        acc += __shfl_xor(acc, 2);
        if (q == 0) lg[n] = acc;
        __syncthreads();
        if (tid < 64) {
            float v = lg[tid];
            float mx = v;
            for (int off = 32; off >= 1; off >>= 1) mx = fmaxf(mx, __shfl_xor(mx, off));
            float e = __expf(v - mx);
            float s = e;
            for (int off = 32; off >= 1; off >>= 1) s += __shfl_xor(s, off);
            pref[((size_t)rr*TOK + bs)*64 + tid] = im * e / s;
        }
    }
}

// Sum pref over s: wsum[r][b][n] = sum_s pref[r][b*1024+s][n]
__global__ __launch_bounds__(256) void reduce_router(
    const float* __restrict__ pref, float* __restrict__ wsum)
{
    int rb = blockIdx.x;            // 0..39  (r*8 + b)
    int tid = threadIdx.x;
    int n = tid & 63, sg = tid >> 6;
    const float* p = pref + (size_t)rb*1024*64;
    float acc = 0.f;
    for (int s = sg; s < 1024; s += 4) acc += p[(size_t)s*64 + n];
    __shared__ float red[4][64];
    red[sg][n] = acc;
    __syncthreads();
    if (tid < 64)
        wsum[(size_t)rb*64 + tid] = red[0][tid] + red[1][tid] + red[2][tid] + red[3][tid];
}

// Normalize, top-k (k=16 for routers 0,4; k=8 for 1,2,3), renormalize.
__global__ void topk_router(const float* __restrict__ wsum,
                            float* __restrict__ tw, int* __restrict__ ti)
{
    int rb = blockIdx.x;           // r*8+b
    int r  = rb >> 3;
    int lane = threadIdx.x;        // 64 threads = 1 wave
    float v = wsum[(size_t)rb*64 + lane];
    float s = v;
    for (int off = 32; off >= 1; off >>= 1) s += __shfl_xor(s, off);
    v = v / (s + 1e-8f);
    int k = (r == 0 || r == 4) ? 16 : 8;
    __shared__ float tv[16];
    __shared__ int   tix[16];
    float cur = v;
    for (int it = 0; it < k; ++it) {
        float bv = cur; int bi = lane;
        for (int off = 32; off >= 1; off >>= 1) {
            float ov = __shfl_xor(bv, off);
            int   oi = __shfl_xor(bi, off);
            if (ov > bv || (ov == bv && oi < bi)) { bv = ov; bi = oi; }
        }
        if (bi == lane) cur = -1e30f;    // all lanes agree on (bv,bi)
        if (lane == 0) { tv[it] = bv; tix[it] = bi; }
    }
    __syncthreads();
    float s2 = 0.f;
    for (int i = 0; i < k; ++i) s2 += tv[i];
    float inv = 1.f / (s2 + 1e-8f);
    if (lane < k) {
        tw[(size_t)rb*16 + lane] = tv[lane] * inv;
        ti[(size_t)rb*16 + lane] = tix[lane];
    }
}

// out[b][e] = sum_i tw[b][i] * table[ti[b][i]][e]   (e = 0..EPE-1, float4)
__global__ __launch_bounds__(256) void combine_kernel(
    const float* __restrict__ table, const float* __restrict__ tw,
    const int* __restrict__ ti, float* __restrict__ out, int k)
{
    int b = blockIdx.y;
    size_t e = ((size_t)blockIdx.x*256 + threadIdx.x)*4;
    float4 acc = {0.f, 0.f, 0.f, 0.f};
    for (int i = 0; i < k; ++i) {
        float w = tw[b*16 + i];
        int  idx = ti[b*16 + i];
        float4 t = *(const float4*)&table[(size_t)idx*EPE + e];
        acc.x += w*t.x; acc.y += w*t.y; acc.z += w*t.z; acc.w += w*t.w;
    }
    *(float4*)&out[(size_t)b*EPE + e] = acc;
}

// ======================================================================
// Generic f32 tiled GEMM: C[b] = alpha * A[b] (MxK) * B[b] (KxN or N x K^T)
// 64x64 tile, 256 threads, 4x4 micro-tile. M,N,K multiples of 64.
// ======================================================================
__global__ __launch_bounds__(256) void gemm_kernel(
    const float* __restrict__ A, const float* __restrict__ Bm, float* __restrict__ C,
    int M, int N, int K, long long sA, long long sB, long long sC,
    float alpha, int transB)
{
    A  += (size_t)blockIdx.z * sA;
    Bm += (size_t)blockIdx.z * sB;
    C  += (size_t)blockIdx.z * sC;
    __shared__ __align__(16) float As[16][68];
    __shared__ __align__(16) float Bs[16][68];
    int tid = threadIdx.x;
    int tx = tid & 15, ty = tid >> 4;
    int row0 = blockIdx.y * 64, col0 = blockIdx.x * 64;
    float acc[4][4] = {};
    for (int k0 = 0; k0 < K; k0 += 16) {
        __syncthreads();
#pragma unroll
        for (int i = 0; i < 4; ++i) {
            int idx = tid + 256*i;
            int m2 = idx >> 4, kk = idx & 15;
            As[kk][m2] = A[(size_t)(row0 + m2)*K + k0 + kk];
        }
        if (!transB) {
#pragma unroll
            for (int i = 0; i < 4; ++i) {
                int idx = tid + 256*i;
                int kk = idx >> 6, n2 = idx & 63;
                Bs[kk][n2] = Bm[(size_t)(k0 + kk)*N + col0 + n2];
            }
        } else {
#pragma unroll
            for (int i = 0; i < 4; ++i) {
                int idx = tid + 256*i;
                int n2 = idx >> 4, kk = idx & 15;
                Bs[kk][n2] = Bm[(size_t)(col0 + n2)*K + k0 + kk];
            }
        }
        __syncthreads();
#pragma unroll
        for (int kk = 0; kk < 16; ++kk) {
            float4 a = *(const float4*)&As[kk][ty*4];
            float4 b = *(const float4*)&Bs[kk][tx*4];
            float av[4] = {a.x, a.y, a.z, a.w};
            float bv[4] = {b.x, b.y, b.z, b.w};
#pragma unroll
            for (int i = 0; i < 4; ++i)
#pragma unroll
                for (int j = 0; j < 4; ++j)
                    acc[i][j] += av[i]*bv[j];
        }
    }
#pragma unroll
    for (int i = 0; i < 4; ++i) {
        float4 r;
        r.x = acc[i][0]*alpha; r.y = acc[i][1]*alpha;
        r.z = acc[i][2]*alpha; r.w = acc[i][3]*alpha;
        *(float4*)&C[(size_t)(row0 + ty*4 + i)*N + col0 + tx*4] = r;
    }
}

// ======================================================================
// Flash-style causal attention. One block per (q-tile 64, head, batch).
// 256 threads: row r = tid/4, lane-group cg = tid%4 owns cols cg*16..+15.
// Each thread keeps a FULL 64-dim partial O over its j-subset; lane-group
// reduced at the end (keeps all register indices static).
// ======================================================================
__global__ __launch_bounds__(256) void attn_kernel(
    const float* __restrict__ Q, const float* __restrict__ K,
    const float* __restrict__ V, float* __restrict__ O)
{
    int qt = blockIdx.x, hh = blockIdx.y, b = blockIdx.z;
    int tid = threadIdx.x;
    __shared__ __align__(16) float Qs[64][65];
    __shared__ __align__(16) float Ks[64][65];
    __shared__ __align__(16) float Vs[64][65];
    const float* Qb = Q + ((size_t)b*Sn + qt*64)*Dn + hh*64;
    for (int i = tid; i < 64*64; i += 256)
        Qs[i >> 6][i & 63] = Qb[(size_t)(i >> 6)*Dn + (i & 63)];
    int r = tid >> 2, cg = tid & 3;
    float m = -1e30f, l = 0.f;
    float o[64];
#pragma unroll
    for (int d = 0; d < 64; ++d) o[d] = 0.f;

    for (int kt = 0; kt <= qt; ++kt) {
        __syncthreads();
        const float* Kb = K + ((size_t)b*Sn + kt*64)*Dn + hh*64;
        const float* Vb = V + ((size_t)b*Sn + kt*64)*Dn + hh*64;
        for (int i = tid; i < 64*64; i += 256) {
            Ks[i >> 6][i & 63] = Kb[(size_t)(i >> 6)*Dn + (i & 63)];
            Vs[i >> 6][i & 63] = Vb[(size_t)(i >> 6)*Dn + (i & 63)];
        }
        __syncthreads();
        float sc[16];
#pragma unroll
        for (int jj = 0; jj < 16; ++jj) sc[jj] = 0.f;
        for (int d = 0; d < 64; ++d) {
            float qd = Qs[r][d];
#pragma unroll
            for (int jj = 0; jj < 16; ++jj)
                sc[jj] += qd * Ks[cg*16 + jj][d];
        }
        float tm = -1e30f;
#pragma unroll
        for (int jj = 0; jj < 16; ++jj) {
            int j = cg*16 + jj;
            sc[jj] *= 0.125f;                        // 1/sqrt(64)
            if (kt == qt && j > r) sc[jj] = -1e30f;  // causal mask
            tm = fmaxf(tm, sc[jj]);
        }
        tm = fmaxf(tm, __shfl_xor(tm, 1));
        tm = fmaxf(tm, __shfl_xor(tm, 2));
        float mn   = fmaxf(m, tm);
        float corr = __expf(m - mn);
        float ps = 0.f;
#pragma unroll
        for (int jj = 0; jj < 16; ++jj) { sc[jj] = __expf(sc[jj] - mn); ps += sc[jj]; }
        ps += __shfl_xor(ps, 1);
        ps += __shfl_xor(ps, 2);
        l = l*corr + ps;
        m = mn;
#pragma unroll
        for (int d = 0; d < 64; ++d) o[d] *= corr;
        for (int jj = 0; jj < 16; ++jj) {
            float p = sc[jj];
            int j = cg*16 + jj;
#pragma unroll
            for (int d = 0; d < 64; ++d) o[d] += p * Vs[j][d];
        }
    }
    // reduce partial O across the 4 lanes of each row group
#pragma unroll
    for (int d = 0; d < 64; ++d) {
        o[d] += __shfl_xor(o[d], 1);
        o[d] += __shfl_xor(o[d], 2);
    }
    float inv = 1.f / l;
    float* Ob = O + ((size_t)b*Sn + qt*64 + r)*Dn + hh*64 + cg*16;
#pragma unroll
    for (int base = 0; base < 4; ++base) {
        if (cg == base) {
#pragma unroll
            for (int dd = 0; dd < 16; ++dd)
                Ob[dd] = o[base*16 + dd] * inv;    // static register indices
        }
    }
}

// ======================================================================
// Per-token top-8 over 4096 knowledge scores + softmax + weighted V gather,
// accumulated into d_out. One block per token (chunked, 1024 tokens/launch).
// ======================================================================
__global__ __launch_bounds__(256) void mem_topk_kernel(
    const float* __restrict__ ksc, const float* __restrict__ kV,
    float* __restrict__ out, int tok0)
{
    int t = blockIdx.x;
    int tid = threadIdx.x;
    const float* row = ksc + (size_t)t*NKn;
    float v[16];
#pragma unroll
    for (int j = 0; j < 16; ++j) v[j] = row[tid + j*256];
    __shared__ float cv[4];  __shared__ int ci[4];
    __shared__ float tv[8];  __shared__ int tix[8];
    for (int it = 0; it < 8; ++it) {
        float bv = -3e38f; int bi = 0x7fffffff;
#pragma unroll
        for (int j = 0; j < 16; ++j) {
            int n = tid + j*256;
            if (v[j] > bv || (v[j] == bv && n < bi)) { bv = v[j]; bi = n; }
        }
        for (int off = 32; off >= 1; off >>= 1) {
            float ov = __shfl_xor(bv, off);
            int   oi = __shfl_xor(bi, off);
            if (ov > bv || (ov == bv && oi < bi)) { bv = ov; bi = oi; }
        }
        if ((tid & 63) == 0) { cv[tid >> 6] = bv; ci[tid >> 6] = bi; }
        __syncthreads();
        if (tid == 0) {
            float fv = cv[0]; int fi = ci[0];
            for (int w = 1; w < 4; ++w)
                if (cv[w] > fv || (cv[w] == fv && ci[w] < fi)) { fv = cv[w]; fi = ci[w]; }
            tv[it] = fv; tix[it] = fi;
        }
        __syncthreads();
        int sel = tix[it];
#pragma unroll
        for (int j = 0; j < 16; ++j)
            if (tid + j*256 == sel) v[j] = -3e38f;   // static index mark-used
        __syncthreads();
    }
    float mx = tv[0];
#pragma unroll
    for (int kx = 1; kx < 8; ++kx) mx = fmaxf(mx, tv[kx]);
    float p[8]; float sum = 0.f;
#pragma unroll
    for (int kx = 0; kx < 8; ++kx) { p[kx] = __expf(tv[kx] - mx); sum += p[kx]; }
    float invs = 1.f / sum;
    float4 acc = {0.f, 0.f, 0.f, 0.f};
#pragma unroll
    for (int kx = 0; kx < 8; ++kx) {
        float pk = p[kx]*invs;
        float4 vv = *(const float4*)&kV[(size_t)tix[kx]*Dn + tid*4];
        acc.x += pk*vv.x; acc.y += pk*vv.y; acc.z += pk*vv.z; acc.w += pk*vv.w;
    }
    float* op = out + ((size_t)(tok0 + t))*Dn + tid*4;
    float4 cur = *(const float4*)op;
    cur.x += acc.x; cur.y += acc.y; cur.z += acc.z; cur.w += acc.w;
    *(float4*)op = cur;
}

// ======================================================================
extern "C" void kernel_launch(void* const* d_in, const int* in_sizes, int n_in,
                              void* d_out, int out_size, void* d_ws, size_t ws_size,
                              hipStream_t stream)
{
    const float* x          = (const float*)d_in[0];
    const float* imp        = (const float*)d_in[1];
    const float* compress_w = (const float*)d_in[2];
    const float* expQ_w     = (const float*)d_in[3];
    const float* expK_w     = (const float*)d_in[4];
    const float* expV_w     = (const float*)d_in[5];
    const float* memory_w   = (const float*)d_in[6];
    const float* neurons    = (const float*)d_in[7];   // [64, D, R]
    const float* pool       = (const float*)d_in[8];   // [64, R, D]
    const float* kK         = (const float*)d_in[9];   // [4096, R]
    const float* kV         = (const float*)d_in[10];  // [4096, D]
    const float* Wo         = (const float*)d_in[11];  // [D, D]
    float* out = (float*)d_out;

    // ---- workspace layout (~220 MB, 256B aligned) ----
    char* ws = (char*)d_ws;
    size_t off = 0;
    auto alloc = [&](size_t bytes) {
        size_t o = off; off = (off + bytes + 255) & ~(size_t)255; return (void*)(ws + o);
    };
    float* pref = (float*)alloc((size_t)5*TOK*64*4);
    float* wsum = (float*)alloc((size_t)5*Bn*64*4);
    float* tw   = (float*)alloc((size_t)5*Bn*16*4);
    int*   ti   = (int*)  alloc((size_t)5*Bn*16*4);
    float* sh_c = (float*)alloc((size_t)Bn*EPE*4);
    float* sh_m = (float*)alloc((size_t)Bn*EPE*4);
    float* sQ   = (float*)alloc((size_t)Bn*EPE*4);
    float* sK   = (float*)alloc((size_t)Bn*EPE*4);
    float* sV   = (float*)alloc((size_t)Bn*EPE*4);
    float* h    = (float*)alloc((size_t)Bn*Sn*Rn*4);
    float* hm   = (float*)alloc((size_t)Bn*Sn*Rn*4);
    float* Qb   = (float*)alloc((size_t)Bn*Sn*Dn*4);
    float* Kb   = (float*)alloc((size_t)Bn*Sn*Dn*4);
    float* Vb   = (float*)alloc((size_t)Bn*Sn*Dn*4);
    float* Ob   = (float*)alloc((size_t)Bn*Sn*Dn*4);
    float* ksc  = (float*)alloc((size_t)1024*NKn*4);
    (void)ws_size; (void)in_sizes; (void)n_in; (void)out_size;

    // ---- 1. routers ----
    router_kernel<<<TOK, 256, 0, stream>>>(x, imp, compress_w, expQ_w, expK_w,
                                           expV_w, memory_w, pref);
    reduce_router<<<40, 256, 0, stream>>>(pref, wsum);
    topk_router<<<40, 64, 0, stream>>>(wsum, tw, ti);

    // ---- 2. expert combines (router order: 0=c,1=Q,2=K,3=V,4=mem) ----
    dim3 cgrid(EPE/1024, Bn);
    combine_kernel<<<cgrid, 256, 0, stream>>>(neurons, tw + 0*128, ti + 0*128, sh_c, 16);
    combine_kernel<<<cgrid, 256, 0, stream>>>(pool,    tw + 1*128, ti + 1*128, sQ,   8);
    combine_kernel<<<cgrid, 256, 0, stream>>>(pool,    tw + 2*128, ti + 2*128, sK,   8);
    combine_kernel<<<cgrid, 256, 0, stream>>>(pool,    tw + 3*128, ti + 3*128, sV,   8);
    combine_kernel<<<cgrid, 256, 0, stream>>>(neurons, tw + 4*128, ti + 4*128, sh_m, 16);

    // ---- 3. h = x @ shared_c ; hm = x @ shared_m  (per batch) ----
    gemm_kernel<<<dim3(Rn/64, Sn/64, Bn), 256, 0, stream>>>(
        x, sh_c, h, Sn, Rn, Dn, (long long)Sn*Dn, (long long)EPE, (long long)Sn*Rn, 1.f, 0);
    gemm_kernel<<<dim3(Rn/64, Sn/64, Bn), 256, 0, stream>>>(
        x, sh_m, hm, Sn, Rn, Dn, (long long)Sn*Dn, (long long)EPE, (long long)Sn*Rn, 1.f, 0);

    // ---- 4. Q/K/V = h @ sharedX ----
    gemm_kernel<<<dim3(Dn/64, Sn/64, Bn), 256, 0, stream>>>(
        h, sQ, Qb, Sn, Dn, Rn, (long long)Sn*Rn, (long long)EPE, (long long)Sn*Dn, 1.f, 0);
    gemm_kernel<<<dim3(Dn/64, Sn/64, Bn), 256, 0, stream>>>(
        h, sK, Kb, Sn, Dn, Rn, (long long)Sn*Rn, (long long)EPE, (long long)Sn*Dn, 1.f, 0);
    gemm_kernel<<<dim3(Dn/64, Sn/64, Bn), 256, 0, stream>>>(
        h, sV, Vb, Sn, Dn, Rn, (long long)Sn*Rn, (long long)EPE, (long long)Sn*Dn, 1.f, 0);

    // ---- 5. causal flash attention ----
    attn_kernel<<<dim3(Sn/64, NHn, Bn), 256, 0, stream>>>(Qb, Kb, Vb, Ob);

    // ---- 6. output projection: d_out = O @ Wo^T ----
    gemm_kernel<<<dim3(Dn/64, Sn/64, Bn), 256, 0, stream>>>(
        Ob, Wo, out, Sn, Dn, Dn, (long long)Sn*Dn, 0LL, (long long)Sn*Dn, 1.f, 1);

    // ---- 7. knowledge memory: chunked kscores GEMM + top-8 + gather-add ----
    for (int c = 0; c < 8; ++c) {
        gemm_kernel<<<dim3(NKn/64, 1024/64, 1), 256, 0, stream>>>(
            hm + (size_t)c*1024*Rn, kK, ksc, 1024, NKn, Rn, 0LL, 0LL, 0LL,
            0.0625f /* 1/sqrt(256) */, 1);
        mem_topk_kernel<<<1024, 256, 0, stream>>>(ksc, kV, out, c*1024);
    }
}

// Round 2
// 1692.463 us; speedup vs baseline: 1.9225x; 1.9225x over previous
//
#include <hip/hip_runtime.h>

// Problem constants
#define Bn   8
#define Sn   1024
#define Dn   1024
#define Rn   256
#define NHn  16
#define DHn  64
#define NKn  4096
#define TOK  (Bn*Sn)        // 8192 tokens
#define EPE  (Dn*Rn)        // 262144 elements per expert table entry

typedef __attribute__((ext_vector_type(8))) short short8;   // 8 bf16 (4 VGPR)
typedef __attribute__((ext_vector_type(4))) float f32x4;

__device__ inline unsigned short f2bf(float f) {
    union { float f; unsigned u; } v; v.f = f;
    unsigned r = v.u + 0x7fffu + ((v.u >> 16) & 1u);   // round-to-nearest-even
    return (unsigned short)(r >> 16);
}

// ======================================================================
// Router: per token, logits for 5 routers (64 experts each), softmax,
// multiply by importance, write pref[r][tok][64].
// ======================================================================
__global__ __launch_bounds__(256) void router_kernel(
    const float* __restrict__ x, const float* __restrict__ imp,
    const float* __restrict__ w0, const float* __restrict__ w1,
    const float* __restrict__ w2, const float* __restrict__ w3,
    const float* __restrict__ w4, float* __restrict__ pref)
{
    int bs  = blockIdx.x;          // token 0..8191
    int tid = threadIdx.x;
    __shared__ __align__(16) float xs[Dn];
    __shared__ float lg[64];
    for (int i = tid; i < Dn; i += 256) xs[i] = x[(size_t)bs*Dn + i];
    float im = imp[bs];
    int n = tid >> 2, q = tid & 3;           // 4 lanes per expert logit
    const float* ws[5] = {w0, w1, w2, w3, w4};
#pragma unroll
    for (int rr = 0; rr < 5; ++rr) {
        __syncthreads();
        const float* w = ws[rr] + (size_t)n*Dn;
        float acc = 0.f;
#pragma unroll 4
        for (int j = 0; j < 64; ++j) {
            int i4 = (j*4 + q)*4;
            float4 xv = *(const float4*)&xs[i4];
            float4 wv = *(const float4*)&w[i4];
            acc += xv.x*wv.x + xv.y*wv.y + xv.z*wv.z + xv.w*wv.w;
        }
        acc += __shfl_xor(acc, 1);
        acc += __shfl_xor(acc, 2);
        if (q == 0) lg[n] = acc;
        __syncthreads();
        if (tid < 64) {
            float v = lg[tid];
            float mx = v;
            for (int off = 32; off >= 1; off >>= 1) mx = fmaxf(mx, __shfl_xor(mx, off));
            float e = __expf(v - mx);
            float s = e;
            for (int off = 32; off >= 1; off >>= 1) s += __shfl_xor(s, off);
            pref[((size_t)rr*TOK + bs)*64 + tid] = im * e / s;
        }
    }
}

// Sum pref over s: wsum[r][b][n] = sum_s pref[r][b*1024+s][n]
__global__ __launch_bounds__(256) void reduce_router(
    const float* __restrict__ pref, float* __restrict__ wsum)
{
    int rb = blockIdx.x;            // 0..39  (r*8 + b)
    int tid = threadIdx.x;
    int n = tid & 63, sg = tid >> 6;
    const float* p = pref + (size_t)rb*1024*64;
    float acc = 0.f;
    for (int s = sg; s < 1024; s += 4) acc += p[(size_t)s*64 + n];
    __shared__ float red[4][64];
    red[sg][n] = acc;
    __syncthreads();
    if (tid < 64)
        wsum[(size_t)rb*64 + tid] = red[0][tid] + red[1][tid] + red[2][tid] + red[3][tid];
}

// Normalize, top-k (k=16 for routers 0,4; k=8 for 1,2,3), renormalize.
__global__ void topk_router(const float* __restrict__ wsum,
                            float* __restrict__ tw, int* __restrict__ ti)
{
    int rb = blockIdx.x;           // r*8+b
    int r  = rb >> 3;
    int lane = threadIdx.x;        // 64 threads = 1 wave
    float v = wsum[(size_t)rb*64 + lane];
    float s = v;
    for (int off = 32; off >= 1; off >>= 1) s += __shfl_xor(s, off);
    v = v / (s + 1e-8f);
    int k = (r == 0 || r == 4) ? 16 : 8;
    __shared__ float tv[16];
    __shared__ int   tix[16];
    float cur = v;
    for (int it = 0; it < k; ++it) {
        float bv = cur; int bi = lane;
        for (int off = 32; off >= 1; off >>= 1) {
            float ov = __shfl_xor(bv, off);
            int   oi = __shfl_xor(bi, off);
            if (ov > bv || (ov == bv && oi < bi)) { bv = ov; bi = oi; }
        }
        if (bi == lane) cur = -1e30f;    // all lanes agree on (bv,bi)
        if (lane == 0) { tv[it] = bv; tix[it] = bi; }
    }
    __syncthreads();
    float s2 = 0.f;
    for (int i = 0; i < k; ++i) s2 += tv[i];
    float inv = 1.f / (s2 + 1e-8f);
    if (lane < k) {
        tw[(size_t)rb*16 + lane] = tv[lane] * inv;
        ti[(size_t)rb*16 + lane] = tix[lane];
    }
}

// out[b][e] = sum_i tw[b][i] * table[ti[b][i]][e]   (e = 0..EPE-1, float4)
__global__ __launch_bounds__(256) void combine_kernel(
    const float* __restrict__ table, const float* __restrict__ tw,
    const int* __restrict__ ti, float* __restrict__ out, int k)
{
    int b = blockIdx.y;
    size_t e = ((size_t)blockIdx.x*256 + threadIdx.x)*4;
    float4 acc = {0.f, 0.f, 0.f, 0.f};
    for (int i = 0; i < k; ++i) {
        float w = tw[b*16 + i];
        int  idx = ti[b*16 + i];
        float4 t = *(const float4*)&table[(size_t)idx*EPE + e];
        acc.x += w*t.x; acc.y += w*t.y; acc.z += w*t.z; acc.w += w*t.w;
    }
    *(float4*)&out[(size_t)b*EPE + e] = acc;
}

// ======================================================================
// Generic f32 tiled GEMM: C[b] = alpha * A[b] (MxK) * B[b] (KxN or N x K^T)
// 64x64 tile, 256 threads, 4x4 micro-tile. M,N,K multiples of 64.
// ======================================================================
__global__ __launch_bounds__(256) void gemm_kernel(
    const float* __restrict__ A, const float* __restrict__ Bm, float* __restrict__ C,
    int M, int N, int K, long long sA, long long sB, long long sC,
    float alpha, int transB)
{
    A  += (size_t)blockIdx.z * sA;
    Bm += (size_t)blockIdx.z * sB;
    C  += (size_t)blockIdx.z * sC;
    __shared__ __align__(16) float As[16][68];
    __shared__ __align__(16) float Bs[16][68];
    int tid = threadIdx.x;
    int tx = tid & 15, ty = tid >> 4;
    int row0 = blockIdx.y * 64, col0 = blockIdx.x * 64;
    float acc[4][4] = {};
    for (int k0 = 0; k0 < K; k0 += 16) {
        __syncthreads();
#pragma unroll
        for (int i = 0; i < 4; ++i) {
            int idx = tid + 256*i;
            int m2 = idx >> 4, kk = idx & 15;
            As[kk][m2] = A[(size_t)(row0 + m2)*K + k0 + kk];
        }
        if (!transB) {
#pragma unroll
            for (int i = 0; i < 4; ++i) {
                int idx = tid + 256*i;
                int kk = idx >> 6, n2 = idx & 63;
                Bs[kk][n2] = Bm[(size_t)(k0 + kk)*N + col0 + n2];
            }
        } else {
#pragma unroll
            for (int i = 0; i < 4; ++i) {
                int idx = tid + 256*i;
                int n2 = idx >> 4, kk = idx & 15;
                Bs[kk][n2] = Bm[(size_t)(col0 + n2)*K + k0 + kk];
            }
        }
        __syncthreads();
#pragma unroll
        for (int kk = 0; kk < 16; ++kk) {
            float4 a = *(const float4*)&As[kk][ty*4];
            float4 b = *(const float4*)&Bs[kk][tx*4];
            float av[4] = {a.x, a.y, a.z, a.w};
            float bv[4] = {b.x, b.y, b.z, b.w};
#pragma unroll
            for (int i = 0; i < 4; ++i)
#pragma unroll
                for (int j = 0; j < 4; ++j)
                    acc[i][j] += av[i]*bv[j];
        }
    }
#pragma unroll
    for (int i = 0; i < 4; ++i) {
        float4 r;
        r.x = acc[i][0]*alpha; r.y = acc[i][1]*alpha;
        r.z = acc[i][2]*alpha; r.w = acc[i][3]*alpha;
        *(float4*)&C[(size_t)(row0 + ty*4 + i)*N + col0 + tx*4] = r;
    }
}

// ======================================================================
// MFMA bf16 flash attention. Block = 256 threads = 4 waves, one 64-row
// q-tile per block; wave w owns q rows 16w..16w+15. KVBLK = 64.
// mfma_f32_16x16x32_bf16 layouts (m89-verified):
//   A: row = lane&15,  k = (lane>>4)*8 + elem   (8 bf16 / lane)
//   B: col = lane&15,  k = (lane>>4)*8 + elem
//   C/D: col = lane&15, row = (lane>>4)*4 + reg
// K staged [kv][64] bf16 (+8 pad, keeps 16B align); V staged transposed
// [d][kv]; P round-trips through LDS to convert D-layout -> A-layout.
// ======================================================================
#define PADK 72

__global__ __launch_bounds__(256) void attn_mfma_kernel(
    const float* __restrict__ Q, const float* __restrict__ K,
    const float* __restrict__ V, float* __restrict__ O)
{
    int qt = blockIdx.x, hh = blockIdx.y, b = blockIdx.z;
    int tid  = threadIdx.x;
    int wave = tid >> 6, lane = tid & 63;
    int lr = lane & 15, lg = lane >> 4;

    __shared__ __align__(16) unsigned short Kt[64][PADK];
    __shared__ __align__(16) unsigned short Vt[64][PADK];   // Vt[d][kv]
    __shared__ __align__(16) unsigned short Pt[64][PADK];

    // ---- Q A-frags for this wave's 16-row band (once per block) ----
    const float* Qrow = Q + ((size_t)b*Sn + (size_t)qt*64 + wave*16 + lr)*Dn + hh*64;
    short8 qf0, qf1;
    {
        float4 a0 = *(const float4*)&Qrow[lg*8];
        float4 a1 = *(const float4*)&Qrow[lg*8 + 4];
        float4 b0 = *(const float4*)&Qrow[32 + lg*8];
        float4 b1 = *(const float4*)&Qrow[32 + lg*8 + 4];
        qf0[0]=f2bf(a0.x); qf0[1]=f2bf(a0.y); qf0[2]=f2bf(a0.z); qf0[3]=f2bf(a0.w);
        qf0[4]=f2bf(a1.x); qf0[5]=f2bf(a1.y); qf0[6]=f2bf(a1.z); qf0[7]=f2bf(a1.w);
        qf1[0]=f2bf(b0.x); qf1[1]=f2bf(b0.y); qf1[2]=f2bf(b0.z); qf1[3]=f2bf(b0.w);
        qf1[4]=f2bf(b1.x); qf1[5]=f2bf(b1.y); qf1[6]=f2bf(b1.z); qf1[7]=f2bf(b1.w);
    }

    f32x4 o[4];
#pragma unroll
    for (int ct = 0; ct < 4; ++ct) o[ct] = (f32x4){0.f,0.f,0.f,0.f};
    float m[4]  = {-1e30f,-1e30f,-1e30f,-1e30f};
    float l[4]  = {0.f,0.f,0.f,0.f};

    for (int kt = 0; kt <= qt; ++kt) {
        __syncthreads();   // prior iter's LDS reads done
        // ---- stage K[kv][d] -> bf16 (coalesced global reads) ----
#pragma unroll
        for (int it = 0; it < 2; ++it) {
            int idx = tid + it*256;               // 0..511
            int kv = idx >> 3, d0 = (idx & 7)*8;
            const float* src = K + ((size_t)b*Sn + (size_t)kt*64 + kv)*Dn + hh*64 + d0;
            float4 f0 = *(const float4*)src;
            float4 f1 = *(const float4*)(src + 4);
            short8 w;
            w[0]=f2bf(f0.x); w[1]=f2bf(f0.y); w[2]=f2bf(f0.z); w[3]=f2bf(f0.w);
            w[4]=f2bf(f1.x); w[5]=f2bf(f1.y); w[6]=f2bf(f1.z); w[7]=f2bf(f1.w);
            *(short8*)&Kt[kv][d0] = w;
        }
        // ---- stage V transposed: Vt[d][kv] (conflict-free LDS writes) ----
#pragma unroll
        for (int it = 0; it < 2; ++it) {
            int idx = tid + it*256;
            int kv = idx & 63, d0 = (idx >> 6)*8;   // d0 in {0..56}
            const float* src = V + ((size_t)b*Sn + (size_t)kt*64 + kv)*Dn + hh*64 + d0;
            float4 f0 = *(const float4*)src;
            float4 f1 = *(const float4*)(src + 4);
            Vt[d0+0][kv] = f2bf(f0.x); Vt[d0+1][kv] = f2bf(f0.y);
            Vt[d0+2][kv] = f2bf(f0.z); Vt[d0+3][kv] = f2bf(f0.w);
            Vt[d0+4][kv] = f2bf(f1.x); Vt[d0+5][kv] = f2bf(f1.y);
            Vt[d0+6][kv] = f2bf(f1.z); Vt[d0+7][kv] = f2bf(f1.w);
        }
        __syncthreads();

        // ---- S = Q K^T (per-wave 16x64 tile) ----
        f32x4 s[4];
#pragma unroll
        for (int ct = 0; ct < 4; ++ct) {
            s[ct] = (f32x4){0.f,0.f,0.f,0.f};
            short8 k0 = *(const short8*)&Kt[ct*16 + lr][lg*8];
            short8 k1 = *(const short8*)&Kt[ct*16 + lr][32 + lg*8];
            s[ct] = __builtin_amdgcn_mfma_f32_16x16x32_bf16(qf0, k0, s[ct], 0, 0, 0);
            s[ct] = __builtin_amdgcn_mfma_f32_16x16x32_bf16(qf1, k1, s[ct], 0, 0, 0);
        }

        // ---- scale + causal mask + row max ----
        float mx[4] = {-1e30f,-1e30f,-1e30f,-1e30f};
        int qg0 = qt*64 + wave*16 + lg*4;            // global q of reg 0
#pragma unroll
        for (int ct = 0; ct < 4; ++ct) {
            int kvg = kt*64 + ct*16 + lr;            // global kv of this lane-col
#pragma unroll
            for (int r = 0; r < 4; ++r) {
                float v = s[ct][r] * 0.125f;         // 1/sqrt(64)
                if (kt == qt && kvg > qg0 + r) v = -1e30f;
                s[ct][r] = v;
                mx[r] = fmaxf(mx[r], v);
            }
        }
#pragma unroll
        for (int r = 0; r < 4; ++r) {
            mx[r] = fmaxf(mx[r], __shfl_xor(mx[r], 1));
            mx[r] = fmaxf(mx[r], __shfl_xor(mx[r], 2));
            mx[r] = fmaxf(mx[r], __shfl_xor(mx[r], 4));
            mx[r] = fmaxf(mx[r], __shfl_xor(mx[r], 8));
        }

        // ---- online softmax update ----
        float corr[4], ps[4] = {0.f,0.f,0.f,0.f};
#pragma unroll
        for (int r = 0; r < 4; ++r) {
            float mn = fmaxf(m[r], mx[r]);
            corr[r] = __expf(m[r] - mn);
            m[r] = mn;
        }
#pragma unroll
        for (int ct = 0; ct < 4; ++ct)
#pragma unroll
            for (int r = 0; r < 4; ++r) {
                float e = __expf(s[ct][r] - m[r]);
                s[ct][r] = e;
                ps[r] += e;
            }
#pragma unroll
        for (int r = 0; r < 4; ++r) {
            ps[r] += __shfl_xor(ps[r], 1);
            ps[r] += __shfl_xor(ps[r], 2);
            ps[r] += __shfl_xor(ps[r], 4);
            ps[r] += __shfl_xor(ps[r], 8);
            l[r] = l[r]*corr[r] + ps[r];
#pragma unroll
            for (int ct = 0; ct < 4; ++ct) o[ct][r] *= corr[r];
        }

        // ---- P (D-layout) -> LDS bf16 (wave-private rows) ----
#pragma unroll
        for (int ct = 0; ct < 4; ++ct)
#pragma unroll
            for (int r = 0; r < 4; ++r)
                Pt[wave*16 + lg*4 + r][ct*16 + lr] = f2bf(s[ct][r]);
        __syncthreads();

        // ---- O += P V  (A-frags from Pt, B-frags from Vt) ----
        short8 pa0 = *(const short8*)&Pt[wave*16 + lr][lg*8];
        short8 pa1 = *(const short8*)&Pt[wave*16 + lr][32 + lg*8];
#pragma unroll
        for (int ct = 0; ct < 4; ++ct) {
            short8 v0 = *(const short8*)&Vt[ct*16 + lr][lg*8];
            short8 v1 = *(const short8*)&Vt[ct*16 + lr][32 + lg*8];
            o[ct] = __builtin_amdgcn_mfma_f32_16x16x32_bf16(pa0, v0, o[ct], 0, 0, 0);
            o[ct] = __builtin_amdgcn_mfma_f32_16x16x32_bf16(pa1, v1, o[ct], 0, 0, 0);
        }
    }

    // ---- epilogue: O / l ----
    float* Op = O + ((size_t)b*Sn + (size_t)qt*64 + wave*16 + lg*4)*Dn + hh*64 + lr;
#pragma unroll
    for (int r = 0; r < 4; ++r) {
        float inv = 1.f / l[r];
#pragma unroll
        for (int ct = 0; ct < 4; ++ct)
            Op[(size_t)r*Dn + ct*16] = o[ct][r] * inv;
    }
}

// ======================================================================
// Per-token top-8 over 4096 knowledge scores + softmax + weighted V gather,
// accumulated into d_out. One block per token (chunked, 1024 tokens/launch).
// ======================================================================
__global__ __launch_bounds__(256) void mem_topk_kernel(
    const float* __restrict__ ksc, const float* __restrict__ kV,
    float* __restrict__ out, int tok0)
{
    int t = blockIdx.x;
    int tid = threadIdx.x;
    const float* row = ksc + (size_t)t*NKn;
    float v[16];
#pragma unroll
    for (int j = 0; j < 16; ++j) v[j] = row[tid + j*256];
    __shared__ float cv[4];  __shared__ int ci[4];
    __shared__ float tv[8];  __shared__ int tix[8];
    for (int it = 0; it < 8; ++it) {
        float bv = -3e38f; int bi = 0x7fffffff;
#pragma unroll
        for (int j = 0; j < 16; ++j) {
            int n = tid + j*256;
            if (v[j] > bv || (v[j] == bv && n < bi)) { bv = v[j]; bi = n; }
        }
        for (int off = 32; off >= 1; off >>= 1) {
            float ov = __shfl_xor(bv, off);
            int   oi = __shfl_xor(bi, off);
            if (ov > bv || (ov == bv && oi < bi)) { bv = ov; bi = oi; }
        }
        if ((tid & 63) == 0) { cv[tid >> 6] = bv; ci[tid >> 6] = bi; }
        __syncthreads();
        if (tid == 0) {
            float fv = cv[0]; int fi = ci[0];
            for (int w = 1; w < 4; ++w)
                if (cv[w] > fv || (cv[w] == fv && ci[w] < fi)) { fv = cv[w]; fi = ci[w]; }
            tv[it] = fv; tix[it] = fi;
        }
        __syncthreads();
        int sel = tix[it];
#pragma unroll
        for (int j = 0; j < 16; ++j)
            if (tid + j*256 == sel) v[j] = -3e38f;
        __syncthreads();
    }
    float mx = tv[0];
#pragma unroll
    for (int kx = 1; kx < 8; ++kx) mx = fmaxf(mx, tv[kx]);
    float p[8]; float sum = 0.f;
#pragma unroll
    for (int kx = 0; kx < 8; ++kx) { p[kx] = __expf(tv[kx] - mx); sum += p[kx]; }
    float invs = 1.f / sum;
    float4 acc = {0.f, 0.f, 0.f, 0.f};
#pragma unroll
    for (int kx = 0; kx < 8; ++kx) {
        float pk = p[kx]*invs;
        float4 vv = *(const float4*)&kV[(size_t)tix[kx]*Dn + tid*4];
        acc.x += pk*vv.x; acc.y += pk*vv.y; acc.z += pk*vv.z; acc.w += pk*vv.w;
    }
    float* op = out + ((size_t)(tok0 + t))*Dn + tid*4;
    float4 cur = *(const float4*)op;
    cur.x += acc.x; cur.y += acc.y; cur.z += acc.z; cur.w += acc.w;
    *(float4*)op = cur;
}

// ======================================================================
extern "C" void kernel_launch(void* const* d_in, const int* in_sizes, int n_in,
                              void* d_out, int out_size, void* d_ws, size_t ws_size,
                              hipStream_t stream)
{
    const float* x          = (const float*)d_in[0];
    const float* imp        = (const float*)d_in[1];
    const float* compress_w = (const float*)d_in[2];
    const float* expQ_w     = (const float*)d_in[3];
    const float* expK_w     = (const float*)d_in[4];
    const float* expV_w     = (const float*)d_in[5];
    const float* memory_w   = (const float*)d_in[6];
    const float* neurons    = (const float*)d_in[7];   // [64, D, R]
    const float* pool       = (const float*)d_in[8];   // [64, R, D]
    const float* kK         = (const float*)d_in[9];   // [4096, R]
    const float* kV         = (const float*)d_in[10];  // [4096, D]
    const float* Wo         = (const float*)d_in[11];  // [D, D]
    float* out = (float*)d_out;

    // ---- workspace layout (~220 MB, 256B aligned) ----
    char* ws = (char*)d_ws;
    size_t off = 0;
    auto alloc = [&](size_t bytes) {
        size_t o = off; off = (off + bytes + 255) & ~(size_t)255; return (void*)(ws + o);
    };
    float* pref = (float*)alloc((size_t)5*TOK*64*4);
    float* wsum = (float*)alloc((size_t)5*Bn*64*4);
    float* tw   = (float*)alloc((size_t)5*Bn*16*4);
    int*   ti   = (int*)  alloc((size_t)5*Bn*16*4);
    float* sh_c = (float*)alloc((size_t)Bn*EPE*4);
    float* sh_m = (float*)alloc((size_t)Bn*EPE*4);
    float* sQ   = (float*)alloc((size_t)Bn*EPE*4);
    float* sK   = (float*)alloc((size_t)Bn*EPE*4);
    float* sV   = (float*)alloc((size_t)Bn*EPE*4);
    float* h    = (float*)alloc((size_t)Bn*Sn*Rn*4);
    float* hm   = (float*)alloc((size_t)Bn*Sn*Rn*4);
    float* Qb   = (float*)alloc((size_t)Bn*Sn*Dn*4);
    float* Kb   = (float*)alloc((size_t)Bn*Sn*Dn*4);
    float* Vb   = (float*)alloc((size_t)Bn*Sn*Dn*4);
    float* Ob   = (float*)alloc((size_t)Bn*Sn*Dn*4);
    float* ksc  = (float*)alloc((size_t)1024*NKn*4);
    (void)ws_size; (void)in_sizes; (void)n_in; (void)out_size;

    // ---- 1. routers ----
    router_kernel<<<TOK, 256, 0, stream>>>(x, imp, compress_w, expQ_w, expK_w,
                                           expV_w, memory_w, pref);
    reduce_router<<<40, 256, 0, stream>>>(pref, wsum);
    topk_router<<<40, 64, 0, stream>>>(wsum, tw, ti);

    // ---- 2. expert combines (router order: 0=c,1=Q,2=K,3=V,4=mem) ----
    dim3 cgrid(EPE/1024, Bn);
    combine_kernel<<<cgrid, 256, 0, stream>>>(neurons, tw + 0*128, ti + 0*128, sh_c, 16);
    combine_kernel<<<cgrid, 256, 0, stream>>>(pool,    tw + 1*128, ti + 1*128, sQ,   8);
    combine_kernel<<<cgrid, 256, 0, stream>>>(pool,    tw + 2*128, ti + 2*128, sK,   8);
    combine_kernel<<<cgrid, 256, 0, stream>>>(pool,    tw + 3*128, ti + 3*128, sV,   8);
    combine_kernel<<<cgrid, 256, 0, stream>>>(neurons, tw + 4*128, ti + 4*128, sh_m, 16);

    // ---- 3. h = x @ shared_c ; hm = x @ shared_m  (per batch) ----
    gemm_kernel<<<dim3(Rn/64, Sn/64, Bn), 256, 0, stream>>>(
        x, sh_c, h, Sn, Rn, Dn, (long long)Sn*Dn, (long long)EPE, (long long)Sn*Rn, 1.f, 0);
    gemm_kernel<<<dim3(Rn/64, Sn/64, Bn), 256, 0, stream>>>(
        x, sh_m, hm, Sn, Rn, Dn, (long long)Sn*Dn, (long long)EPE, (long long)Sn*Rn, 1.f, 0);

    // ---- 4. Q/K/V = h @ sharedX ----
    gemm_kernel<<<dim3(Dn/64, Sn/64, Bn), 256, 0, stream>>>(
        h, sQ, Qb, Sn, Dn, Rn, (long long)Sn*Rn, (long long)EPE, (long long)Sn*Dn, 1.f, 0);
    gemm_kernel<<<dim3(Dn/64, Sn/64, Bn), 256, 0, stream>>>(
        h, sK, Kb, Sn, Dn, Rn, (long long)Sn*Rn, (long long)EPE, (long long)Sn*Dn, 1.f, 0);
    gemm_kernel<<<dim3(Dn/64, Sn/64, Bn), 256, 0, stream>>>(
        h, sV, Vb, Sn, Dn, Rn, (long long)Sn*Rn, (long long)EPE, (long long)Sn*Dn, 1.f, 0);

    // ---- 5. causal flash attention (bf16 MFMA) ----
    attn_mfma_kernel<<<dim3(Sn/64, NHn, Bn), 256, 0, stream>>>(Qb, Kb, Vb, Ob);

    // ---- 6. output projection: d_out = O @ Wo^T ----
    gemm_kernel<<<dim3(Dn/64, Sn/64, Bn), 256, 0, stream>>>(
        Ob, Wo, out, Sn, Dn, Dn, (long long)Sn*Dn, 0LL, (long long)Sn*Dn, 1.f, 1);

    // ---- 7. knowledge memory: chunked kscores GEMM + top-8 + gather-add ----
    for (int c = 0; c < 8; ++c) {
        gemm_kernel<<<dim3(NKn/64, 1024/64, 1), 256, 0, stream>>>(
            hm + (size_t)c*1024*Rn, kK, ksc, 1024, NKn, Rn, 0LL, 0LL, 0LL,
            0.0625f /* 1/sqrt(256) */, 1);
        mem_topk_kernel<<<1024, 256, 0, stream>>>(ksc, kV, out, c*1024);
    }
}

// Round 4
// 1164.641 us; speedup vs baseline: 2.7937x; 1.4532x over previous
//
#include <hip/hip_runtime.h>

// Problem constants
#define Bn   8
#define Sn   1024
#define Dn   1024
#define Rn   256
#define NHn  16
#define DHn  64
#define NKn  4096
#define TOK  (Bn*Sn)        // 8192 tokens
#define EPE  (Dn*Rn)        // 262144 elements per expert table entry

typedef __attribute__((ext_vector_type(8))) short short8;   // 8 bf16 (4 VGPR)
typedef __attribute__((ext_vector_type(4))) float f32x4;

__device__ inline unsigned short f2bf(float f) {
    union { float f; unsigned u; } v; v.f = f;
    unsigned r = v.u + 0x7fffu + ((v.u >> 16) & 1u);   // round-to-nearest-even
    return (unsigned short)(r >> 16);
}
// split f32 -> hi + lo bf16 (a ~= hi + lo, residual ~2^-18 * a)
__device__ inline void f2bf_split(float f, unsigned short& hi, unsigned short& lo) {
    hi = f2bf(f);
    union { unsigned u; float f; } hv; hv.u = ((unsigned)hi) << 16;
    lo = f2bf(f - hv.f);
}

// ======================================================================
// Split-bf16 MFMA GEMM: C[z] = alpha * A[z](MxK,f32) @ op(B[z]), f32 out.
// splitA/splitB enable double-bf16 passes:
//   acc += Ahi*Bhi  (+ Alo*Bhi if splitA)  (+ Ahi*Blo if splitB)
// Tile 128x64, BK=32, 256 threads = 4 waves (2x2 wave grid, 64x32 each).
// M%128==0, N%64==0, K%32==0.
// mfma_f32_16x16x32_bf16 frag layouts (m89-verified):
//   A: row=lane&15, k=(lane>>4)*8+e ; B: col=lane&15, same k
//   D: col=lane&15, row=(lane>>4)*4+reg
// ======================================================================
__global__ __launch_bounds__(256) void bf16_gemm(
    const float* __restrict__ A, const float* __restrict__ Bm, float* __restrict__ C,
    int M, int N, int K, long long sA, long long sB, long long sC,
    float alpha, int transB, int splitA, int splitB)
{
    A  += (size_t)blockIdx.z * sA;
    Bm += (size_t)blockIdx.z * sB;
    C  += (size_t)blockIdx.z * sC;
    __shared__ __align__(16) unsigned short AsH[128][40];   // [m][k], 80B rows
    __shared__ __align__(16) unsigned short AsL[128][40];
    __shared__ __align__(16) unsigned short BsH[64][40];    // [n][k]
    __shared__ __align__(16) unsigned short BsL[64][40];
    int tid = threadIdx.x;
    int wave = tid >> 6, lane = tid & 63;
    int lr = lane & 15, lg = lane >> 4;
    int wm = (wave >> 1)*64, wn = (wave & 1)*32;
    int row0 = blockIdx.y*128, col0 = blockIdx.x*64;

    f32x4 acc[4][2];
#pragma unroll
    for (int i = 0; i < 4; ++i)
#pragma unroll
        for (int j = 0; j < 2; ++j) acc[i][j] = (f32x4){0.f,0.f,0.f,0.f};

    for (int k0 = 0; k0 < K; k0 += 32) {
        __syncthreads();
        // ---- stage A tile 128x32 ----
#pragma unroll
        for (int g = 0; g < 2; ++g) {
            int idx = tid + g*256;               // 0..511
            int m2 = idx >> 2, kk = (idx & 3)*8;
            const float* src = A + (size_t)(row0 + m2)*K + k0 + kk;
            float4 f0 = *(const float4*)src;
            float4 f1 = *(const float4*)(src + 4);
            float vals[8] = {f0.x,f0.y,f0.z,f0.w,f1.x,f1.y,f1.z,f1.w};
            short8 wh, wl;
#pragma unroll
            for (int e = 0; e < 8; ++e) {
                unsigned short hi, lo; f2bf_split(vals[e], hi, lo);
                wh[e] = (short)hi; wl[e] = (short)lo;
            }
            *(short8*)&AsH[m2][kk] = wh;
            if (splitA) *(short8*)&AsL[m2][kk] = wl;
        }
        // ---- stage B tile 64x32 ----
        if (transB) {                            // B is N x K (row-major)
            int n2 = tid >> 2, kk = (tid & 3)*8;
            const float* src = Bm + (size_t)(col0 + n2)*K + k0 + kk;
            float4 f0 = *(const float4*)src;
            float4 f1 = *(const float4*)(src + 4);
            float vals[8] = {f0.x,f0.y,f0.z,f0.w,f1.x,f1.y,f1.z,f1.w};
            short8 wh, wl;
#pragma unroll
            for (int e = 0; e < 8; ++e) {
                unsigned short hi, lo; f2bf_split(vals[e], hi, lo);
                wh[e] = (short)hi; wl[e] = (short)lo;
            }
            *(short8*)&BsH[n2][kk] = wh;
            if (splitB) *(short8*)&BsL[n2][kk] = wl;
        } else {                                 // B is K x N: transpose into Bs
            int kk = tid >> 3, n0 = (tid & 7)*8;
            const float* src = Bm + (size_t)(k0 + kk)*N + col0 + n0;
            float4 f0 = *(const float4*)src;
            float4 f1 = *(const float4*)(src + 4);
            float vals[8] = {f0.x,f0.y,f0.z,f0.w,f1.x,f1.y,f1.z,f1.w};
#pragma unroll
            for (int e = 0; e < 8; ++e) {
                unsigned short hi, lo; f2bf_split(vals[e], hi, lo);
                BsH[n0+e][kk] = hi;
                if (splitB) BsL[n0+e][kk] = lo;
            }
        }
        __syncthreads();
        // ---- MFMA passes ----
        short8 afH[4], bfH[2];
#pragma unroll
        for (int i = 0; i < 4; ++i) afH[i] = *(const short8*)&AsH[wm + i*16 + lr][lg*8];
#pragma unroll
        for (int j = 0; j < 2; ++j) bfH[j] = *(const short8*)&BsH[wn + j*16 + lr][lg*8];
#pragma unroll
        for (int i = 0; i < 4; ++i)
#pragma unroll
            for (int j = 0; j < 2; ++j)
                acc[i][j] = __builtin_amdgcn_mfma_f32_16x16x32_bf16(afH[i], bfH[j], acc[i][j], 0, 0, 0);
        if (splitA) {
            short8 afL[4];
#pragma unroll
            for (int i = 0; i < 4; ++i) afL[i] = *(const short8*)&AsL[wm + i*16 + lr][lg*8];
#pragma unroll
            for (int i = 0; i < 4; ++i)
#pragma unroll
                for (int j = 0; j < 2; ++j)
                    acc[i][j] = __builtin_amdgcn_mfma_f32_16x16x32_bf16(afL[i], bfH[j], acc[i][j], 0, 0, 0);
        }
        if (splitB) {
            short8 bfL[2];
#pragma unroll
            for (int j = 0; j < 2; ++j) bfL[j] = *(const short8*)&BsL[wn + j*16 + lr][lg*8];
#pragma unroll
            for (int i = 0; i < 4; ++i)
#pragma unroll
                for (int j = 0; j < 2; ++j)
                    acc[i][j] = __builtin_amdgcn_mfma_f32_16x16x32_bf16(afH[i], bfL[j], acc[i][j], 0, 0, 0);
        }
    }
    // ---- epilogue ----
#pragma unroll
    for (int i = 0; i < 4; ++i)
#pragma unroll
        for (int j = 0; j < 2; ++j)
#pragma unroll
            for (int r = 0; r < 4; ++r)
                C[(size_t)(row0 + wm + i*16 + lg*4 + r)*N + col0 + wn + j*16 + lr]
                    = acc[i][j][r] * alpha;
}

// ======================================================================
// Router post: softmax(logits)*importance, partial-sum over 256-token
// chunks. logits [8192][320]; partial [5][8][4][64].
// ======================================================================
__global__ __launch_bounds__(256) void router_post(
    const float* __restrict__ logits, const float* __restrict__ imp,
    float* __restrict__ partial)
{
    int blk = blockIdx.x;                 // 0..159
    int chunk = blk & 3, b = (blk >> 2) & 7, r = blk >> 5;
    int tid = threadIdx.x, lane = tid & 63, wv = tid >> 6;
    float acc = 0.f;
    for (int i = wv; i < 256; i += 4) {
        int t = b*1024 + chunk*256 + i;
        float lgv = logits[(size_t)t*320 + r*64 + lane];
        float mx = lgv;
        for (int off = 32; off >= 1; off >>= 1) mx = fmaxf(mx, __shfl_xor(mx, off));
        float e = __expf(lgv - mx);
        float s = e;
        for (int off = 32; off >= 1; off >>= 1) s += __shfl_xor(s, off);
        acc += imp[t] * e / s;
    }
    __shared__ float red[4][64];
    red[wv][lane] = acc;
    __syncthreads();
    if (tid < 64)
        partial[((size_t)(r*8 + b)*4 + chunk)*64 + tid]
            = red[0][tid] + red[1][tid] + red[2][tid] + red[3][tid];
}

// Normalize, top-k (k=16 for routers 0,4; k=8 for 1,2,3), renormalize.
__global__ void topk_router(const float* __restrict__ partial,
                            float* __restrict__ tw, int* __restrict__ ti)
{
    int rb = blockIdx.x;           // r*8+b
    int r  = rb >> 3;
    int lane = threadIdx.x;        // 64 threads = 1 wave
    float v = partial[((size_t)rb*4 + 0)*64 + lane] + partial[((size_t)rb*4 + 1)*64 + lane]
            + partial[((size_t)rb*4 + 2)*64 + lane] + partial[((size_t)rb*4 + 3)*64 + lane];
    float s = v;
    for (int off = 32; off >= 1; off >>= 1) s += __shfl_xor(s, off);
    v = v / (s + 1e-8f);
    int k = (r == 0 || r == 4) ? 16 : 8;
    __shared__ float tv[16];
    __shared__ int   tix[16];
    float cur = v;
    for (int it = 0; it < k; ++it) {
        float bv = cur; int bi = lane;
        for (int off = 32; off >= 1; off >>= 1) {
            float ov = __shfl_xor(bv, off);
            int   oi = __shfl_xor(bi, off);
            if (ov > bv || (ov == bv && oi < bi)) { bv = ov; bi = oi; }
        }
        if (bi == lane) cur = -1e30f;
        if (lane == 0) { tv[it] = bv; tix[it] = bi; }
    }
    __syncthreads();
    float s2 = 0.f;
    for (int i = 0; i < k; ++i) s2 += tv[i];
    float inv = 1.f / (s2 + 1e-8f);
    if (lane < k) {
        tw[(size_t)rb*16 + lane] = tv[lane] * inv;
        ti[(size_t)rb*16 + lane] = tix[lane];
    }
}

// out[b][e] = sum_i tw[b][i] * table[ti[b][i]][e]
__global__ __launch_bounds__(256) void combine_kernel(
    const float* __restrict__ table, const float* __restrict__ tw,
    const int* __restrict__ ti, float* __restrict__ out, int k)
{
    int b = blockIdx.y;
    size_t e = ((size_t)blockIdx.x*256 + threadIdx.x)*4;
    float4 acc = {0.f, 0.f, 0.f, 0.f};
    for (int i = 0; i < k; ++i) {
        float w = tw[b*16 + i];
        int  idx = ti[b*16 + i];
        float4 t = *(const float4*)&table[(size_t)idx*EPE + e];
        acc.x += w*t.x; acc.y += w*t.y; acc.z += w*t.z; acc.w += w*t.w;
    }
    *(float4*)&out[(size_t)b*EPE + e] = acc;
}

// ======================================================================
// MFMA bf16 flash attention (proven in round 2: 1.95e-3).
// ======================================================================
#define PADK 72

__global__ __launch_bounds__(256) void attn_mfma_kernel(
    const float* __restrict__ Q, const float* __restrict__ K,
    const float* __restrict__ V, float* __restrict__ O)
{
    int qt = blockIdx.x, hh = blockIdx.y, b = blockIdx.z;
    int tid  = threadIdx.x;
    int wave = tid >> 6, lane = tid & 63;
    int lr = lane & 15, lg = lane >> 4;

    __shared__ __align__(16) unsigned short Kt[64][PADK];
    __shared__ __align__(16) unsigned short Vt[64][PADK];   // Vt[d][kv]
    __shared__ __align__(16) unsigned short Pt[64][PADK];

    const float* Qrow = Q + ((size_t)b*Sn + (size_t)qt*64 + wave*16 + lr)*Dn + hh*64;
    short8 qf0, qf1;
    {
        float4 a0 = *(const float4*)&Qrow[lg*8];
        float4 a1 = *(const float4*)&Qrow[lg*8 + 4];
        float4 b0 = *(const float4*)&Qrow[32 + lg*8];
        float4 b1 = *(const float4*)&Qrow[32 + lg*8 + 4];
        qf0[0]=f2bf(a0.x); qf0[1]=f2bf(a0.y); qf0[2]=f2bf(a0.z); qf0[3]=f2bf(a0.w);
        qf0[4]=f2bf(a1.x); qf0[5]=f2bf(a1.y); qf0[6]=f2bf(a1.z); qf0[7]=f2bf(a1.w);
        qf1[0]=f2bf(b0.x); qf1[1]=f2bf(b0.y); qf1[2]=f2bf(b0.z); qf1[3]=f2bf(b0.w);
        qf1[4]=f2bf(b1.x); qf1[5]=f2bf(b1.y); qf1[6]=f2bf(b1.z); qf1[7]=f2bf(b1.w);
    }

    f32x4 o[4];
#pragma unroll
    for (int ct = 0; ct < 4; ++ct) o[ct] = (f32x4){0.f,0.f,0.f,0.f};
    float m[4]  = {-1e30f,-1e30f,-1e30f,-1e30f};
    float l[4]  = {0.f,0.f,0.f,0.f};

    for (int kt = 0; kt <= qt; ++kt) {
        __syncthreads();
#pragma unroll
        for (int it = 0; it < 2; ++it) {
            int idx = tid + it*256;
            int kv = idx >> 3, d0 = (idx & 7)*8;
            const float* src = K + ((size_t)b*Sn + (size_t)kt*64 + kv)*Dn + hh*64 + d0;
            float4 f0 = *(const float4*)src;
            float4 f1 = *(const float4*)(src + 4);
            short8 w;
            w[0]=f2bf(f0.x); w[1]=f2bf(f0.y); w[2]=f2bf(f0.z); w[3]=f2bf(f0.w);
            w[4]=f2bf(f1.x); w[5]=f2bf(f1.y); w[6]=f2bf(f1.z); w[7]=f2bf(f1.w);
            *(short8*)&Kt[kv][d0] = w;
        }
#pragma unroll
        for (int it = 0; it < 2; ++it) {
            int idx = tid + it*256;
            int kv = idx & 63, d0 = (idx >> 6)*8;
            const float* src = V + ((size_t)b*Sn + (size_t)kt*64 + kv)*Dn + hh*64 + d0;
            float4 f0 = *(const float4*)src;
            float4 f1 = *(const float4*)(src + 4);
            Vt[d0+0][kv] = f2bf(f0.x); Vt[d0+1][kv] = f2bf(f0.y);
            Vt[d0+2][kv] = f2bf(f0.z); Vt[d0+3][kv] = f2bf(f0.w);
            Vt[d0+4][kv] = f2bf(f1.x); Vt[d0+5][kv] = f2bf(f1.y);
            Vt[d0+6][kv] = f2bf(f1.z); Vt[d0+7][kv] = f2bf(f1.w);
        }
        __syncthreads();

        f32x4 s[4];
#pragma unroll
        for (int ct = 0; ct < 4; ++ct) {
            s[ct] = (f32x4){0.f,0.f,0.f,0.f};
            short8 k0 = *(const short8*)&Kt[ct*16 + lr][lg*8];
            short8 k1 = *(const short8*)&Kt[ct*16 + lr][32 + lg*8];
            s[ct] = __builtin_amdgcn_mfma_f32_16x16x32_bf16(qf0, k0, s[ct], 0, 0, 0);
            s[ct] = __builtin_amdgcn_mfma_f32_16x16x32_bf16(qf1, k1, s[ct], 0, 0, 0);
        }

        float mx[4] = {-1e30f,-1e30f,-1e30f,-1e30f};
        int qg0 = qt*64 + wave*16 + lg*4;
#pragma unroll
        for (int ct = 0; ct < 4; ++ct) {
            int kvg = kt*64 + ct*16 + lr;
#pragma unroll
            for (int r = 0; r < 4; ++r) {
                float v = s[ct][r] * 0.125f;
                if (kt == qt && kvg > qg0 + r) v = -1e30f;
                s[ct][r] = v;
                mx[r] = fmaxf(mx[r], v);
            }
        }
#pragma unroll
        for (int r = 0; r < 4; ++r) {
            mx[r] = fmaxf(mx[r], __shfl_xor(mx[r], 1));
            mx[r] = fmaxf(mx[r], __shfl_xor(mx[r], 2));
            mx[r] = fmaxf(mx[r], __shfl_xor(mx[r], 4));
            mx[r] = fmaxf(mx[r], __shfl_xor(mx[r], 8));
        }

        float corr[4], ps[4] = {0.f,0.f,0.f,0.f};
#pragma unroll
        for (int r = 0; r < 4; ++r) {
            float mn = fmaxf(m[r], mx[r]);
            corr[r] = __expf(m[r] - mn);
            m[r] = mn;
        }
#pragma unroll
        for (int ct = 0; ct < 4; ++ct)
#pragma unroll
            for (int r = 0; r < 4; ++r) {
                float e = __expf(s[ct][r] - m[r]);
                s[ct][r] = e;
                ps[r] += e;
            }
#pragma unroll
        for (int r = 0; r < 4; ++r) {
            ps[r] += __shfl_xor(ps[r], 1);
            ps[r] += __shfl_xor(ps[r], 2);
            ps[r] += __shfl_xor(ps[r], 4);
            ps[r] += __shfl_xor(ps[r], 8);
            l[r] = l[r]*corr[r] + ps[r];
#pragma unroll
            for (int ct = 0; ct < 4; ++ct) o[ct][r] *= corr[r];
        }

#pragma unroll
        for (int ct = 0; ct < 4; ++ct)
#pragma unroll
            for (int r = 0; r < 4; ++r)
                Pt[wave*16 + lg*4 + r][ct*16 + lr] = f2bf(s[ct][r]);
        __syncthreads();

        short8 pa0 = *(const short8*)&Pt[wave*16 + lr][lg*8];
        short8 pa1 = *(const short8*)&Pt[wave*16 + lr][32 + lg*8];
#pragma unroll
        for (int ct = 0; ct < 4; ++ct) {
            short8 v0 = *(const short8*)&Vt[ct*16 + lr][lg*8];
            short8 v1 = *(const short8*)&Vt[ct*16 + lr][32 + lg*8];
            o[ct] = __builtin_amdgcn_mfma_f32_16x16x32_bf16(pa0, v0, o[ct], 0, 0, 0);
            o[ct] = __builtin_amdgcn_mfma_f32_16x16x32_bf16(pa1, v1, o[ct], 0, 0, 0);
        }
    }

    float* Op = O + ((size_t)b*Sn + (size_t)qt*64 + wave*16 + lg*4)*Dn + hh*64 + lr;
#pragma unroll
    for (int r = 0; r < 4; ++r) {
        float inv = 1.f / l[r];
#pragma unroll
        for (int ct = 0; ct < 4; ++ct)
            Op[(size_t)r*Dn + ct*16] = o[ct][r] * inv;
    }
}

// ======================================================================
// Knowledge memory: approx top-16 scan over bf16 kscores, f32 rescore of
// the 16 candidates vs f32 hm, exact top-8 + softmax + V gather-add.
// ======================================================================
__global__ __launch_bounds__(256) void mem_rescore_kernel(
    const float* __restrict__ ksc,   // [1024][4096] approx scores (scaled)
    const float* __restrict__ hm,    // [8192][256] f32
    const float* __restrict__ kK,    // [4096][256]
    const float* __restrict__ kV,    // [4096][1024]
    float* __restrict__ out, int tok0)
{
    int t = blockIdx.x;
    int tid = threadIdx.x;
    const float* row = ksc + (size_t)t*NKn;
    float v[16];
#pragma unroll
    for (int j = 0; j < 16; ++j) v[j] = row[tid + j*256];
    __shared__ float cv[4];  __shared__ int ci[4];
    __shared__ float tv16[16]; __shared__ int tix16[16];
    // ---- iterative block argmax x16 (ties -> lowest index) ----
    for (int it = 0; it < 16; ++it) {
        float bv = -3e38f; int bi = 0x7fffffff;
#pragma unroll
        for (int j = 0; j < 16; ++j) {
            int n = tid + j*256;
            if (v[j] > bv || (v[j] == bv && n < bi)) { bv = v[j]; bi = n; }
        }
        for (int off = 32; off >= 1; off >>= 1) {
            float ov = __shfl_xor(bv, off);
            int   oi = __shfl_xor(bi, off);
            if (ov > bv || (ov == bv && oi < bi)) { bv = ov; bi = oi; }
        }
        if ((tid & 63) == 0) { cv[tid >> 6] = bv; ci[tid >> 6] = bi; }
        __syncthreads();
        if (tid == 0) {
            float fv = cv[0]; int fi = ci[0];
            for (int w = 1; w < 4; ++w)
                if (cv[w] > fv || (cv[w] == fv && ci[w] < fi)) { fv = cv[w]; fi = ci[w]; }
            tv16[it] = fv; tix16[it] = fi;
        }
        __syncthreads();
        int sel = tix16[it];
#pragma unroll
        for (int j = 0; j < 16; ++j)
            if (tid + j*256 == sel) v[j] = -3e38f;
        __syncthreads();
    }
    // ---- f32 rescore of the 16 candidates ----
    __shared__ float hs[256];
    __shared__ float cs[16];
    __shared__ float sv[8]; __shared__ int si[8];
    hs[tid] = hm[((size_t)(tok0 + t))*Rn + tid];
    __syncthreads();
    {
        int c = tid >> 4, e = tid & 15;
        const float* kr = kK + (size_t)tix16[c]*Rn;
        float d = 0.f;
#pragma unroll
        for (int j = 0; j < 16; ++j) d += hs[e*16 + j] * kr[e*16 + j];
        d += __shfl_xor(d, 1);
        d += __shfl_xor(d, 2);
        d += __shfl_xor(d, 4);
        d += __shfl_xor(d, 8);
        if (e == 0) cs[c] = d * 0.0625f;          // 1/sqrt(256)
    }
    __syncthreads();
    // ---- exact top-8 of 16 (score desc, index asc) ----
    if (tid == 0) {
        unsigned used = 0;
        for (int it = 0; it < 8; ++it) {
            float bv = -3e38f; int bc = -1; int bidx = 0x7fffffff;
            for (int c = 0; c < 16; ++c) {
                if (used & (1u << c)) continue;
                if (cs[c] > bv || (cs[c] == bv && tix16[c] < bidx)) {
                    bv = cs[c]; bc = c; bidx = tix16[c];
                }
            }
            used |= 1u << bc;
            sv[it] = bv; si[it] = tix16[bc];
        }
    }
    __syncthreads();
    // ---- softmax over 8 + weighted V gather, add into out ----
    float mx = sv[0];
#pragma unroll
    for (int kx = 1; kx < 8; ++kx) mx = fmaxf(mx, sv[kx]);
    float p[8]; float sum = 0.f;
#pragma unroll
    for (int kx = 0; kx < 8; ++kx) { p[kx] = __expf(sv[kx] - mx); sum += p[kx]; }
    float invs = 1.f / sum;
    float4 acc = {0.f, 0.f, 0.f, 0.f};
#pragma unroll
    for (int kx = 0; kx < 8; ++kx) {
        float pk = p[kx]*invs;
        float4 vv = *(const float4*)&kV[(size_t)si[kx]*Dn + tid*4];
        acc.x += pk*vv.x; acc.y += pk*vv.y; acc.z += pk*vv.z; acc.w += pk*vv.w;
    }
    float* op = out + ((size_t)(tok0 + t))*Dn + tid*4;
    float4 cur = *(const float4*)op;
    cur.x += acc.x; cur.y += acc.y; cur.z += acc.z; cur.w += acc.w;
    *(float4*)op = cur;
}

// ======================================================================
extern "C" void kernel_launch(void* const* d_in, const int* in_sizes, int n_in,
                              void* d_out, int out_size, void* d_ws, size_t ws_size,
                              hipStream_t stream)
{
    const float* x          = (const float*)d_in[0];
    const float* imp        = (const float*)d_in[1];
    const float* compress_w = (const float*)d_in[2];
    const float* expQ_w     = (const float*)d_in[3];
    const float* expK_w     = (const float*)d_in[4];
    const float* expV_w     = (const float*)d_in[5];
    const float* memory_w   = (const float*)d_in[6];
    const float* neurons    = (const float*)d_in[7];   // [64, D, R]
    const float* pool       = (const float*)d_in[8];   // [64, R, D]
    const float* kK         = (const float*)d_in[9];   // [4096, R]
    const float* kV         = (const float*)d_in[10];  // [4096, D]
    const float* Wo         = (const float*)d_in[11];  // [D, D]
    float* out = (float*)d_out;

    // ---- workspace layout (~211 MB) ----
    char* ws = (char*)d_ws;
    size_t off = 0;
    auto alloc = [&](size_t bytes) {
        size_t o = off; off = (off + bytes + 255) & ~(size_t)255; return (void*)(ws + o);
    };
    float* wcat    = (float*)alloc((size_t)5*64*Dn*4);          // concat router weights
    float* region1 = (float*)alloc((size_t)1024*NKn*4);         // logits OR ksc (aliased)
    float* partial = (float*)alloc((size_t)40*4*64*4);
    float* tw      = (float*)alloc((size_t)5*Bn*16*4);
    int*   ti      = (int*)  alloc((size_t)5*Bn*16*4);
    float* sh_c = (float*)alloc((size_t)Bn*EPE*4);
    float* sh_m = (float*)alloc((size_t)Bn*EPE*4);
    float* sQ   = (float*)alloc((size_t)Bn*EPE*4);
    float* sK   = (float*)alloc((size_t)Bn*EPE*4);
    float* sV   = (float*)alloc((size_t)Bn*EPE*4);
    float* h    = (float*)alloc((size_t)Bn*Sn*Rn*4);
    float* hm   = (float*)alloc((size_t)Bn*Sn*Rn*4);
    float* Qb   = (float*)alloc((size_t)Bn*Sn*Dn*4);
    float* Kb   = (float*)alloc((size_t)Bn*Sn*Dn*4);
    float* Vb   = (float*)alloc((size_t)Bn*Sn*Dn*4);
    float* Ob   = (float*)alloc((size_t)Bn*Sn*Dn*4);
    float* logits = region1;   // [8192][320], dead before ksc is written
    float* ksc    = region1;   // [1024][4096] per chunk
    (void)ws_size; (void)in_sizes; (void)n_in; (void)out_size;

    // ---- 1. routers: concat weights, one split-bf16 GEMM, fused post ----
    hipMemcpyAsync(wcat + 0*64*Dn, compress_w, (size_t)64*Dn*4, hipMemcpyDeviceToDevice, stream);
    hipMemcpyAsync(wcat + 1*64*Dn, expQ_w,     (size_t)64*Dn*4, hipMemcpyDeviceToDevice, stream);
    hipMemcpyAsync(wcat + 2*64*Dn, expK_w,     (size_t)64*Dn*4, hipMemcpyDeviceToDevice, stream);
    hipMemcpyAsync(wcat + 3*64*Dn, expV_w,     (size_t)64*Dn*4, hipMemcpyDeviceToDevice, stream);
    hipMemcpyAsync(wcat + 4*64*Dn, memory_w,   (size_t)64*Dn*4, hipMemcpyDeviceToDevice, stream);
    bf16_gemm<<<dim3(5, 64, 1), 256, 0, stream>>>(
        x, wcat, logits, TOK, 320, Dn, 0LL, 0LL, 0LL, 1.f, 1, 1, 1);
    router_post<<<160, 256, 0, stream>>>(logits, imp, partial);
    topk_router<<<40, 64, 0, stream>>>(partial, tw, ti);

    // ---- 2. expert combines (0=c,1=Q,2=K,3=V,4=mem) ----
    dim3 cgrid(EPE/1024, Bn);
    combine_kernel<<<cgrid, 256, 0, stream>>>(neurons, tw + 0*128, ti + 0*128, sh_c, 16);
    combine_kernel<<<cgrid, 256, 0, stream>>>(pool,    tw + 1*128, ti + 1*128, sQ,   8);
    combine_kernel<<<cgrid, 256, 0, stream>>>(pool,    tw + 2*128, ti + 2*128, sK,   8);
    combine_kernel<<<cgrid, 256, 0, stream>>>(pool,    tw + 3*128, ti + 3*128, sV,   8);
    combine_kernel<<<cgrid, 256, 0, stream>>>(neurons, tw + 4*128, ti + 4*128, sh_m, 16);

    // ---- 3. h = x @ sh_c ; hm = x @ sh_m  (split-bf16, f32-accurate) ----
    bf16_gemm<<<dim3(Rn/64, Sn/128, Bn), 256, 0, stream>>>(
        x, sh_c, h, Sn, Rn, Dn, (long long)Sn*Dn, (long long)EPE, (long long)Sn*Rn, 1.f, 0, 1, 1);
    bf16_gemm<<<dim3(Rn/64, Sn/128, Bn), 256, 0, stream>>>(
        x, sh_m, hm, Sn, Rn, Dn, (long long)Sn*Dn, (long long)EPE, (long long)Sn*Rn, 1.f, 0, 1, 1);

    // ---- 4. Q/K/V = h @ sharedX (split-bf16) ----
    bf16_gemm<<<dim3(Dn/64, Sn/128, Bn), 256, 0, stream>>>(
        h, sQ, Qb, Sn, Dn, Rn, (long long)Sn*Rn, (long long)EPE, (long long)Sn*Dn, 1.f, 0, 1, 1);
    bf16_gemm<<<dim3(Dn/64, Sn/128, Bn), 256, 0, stream>>>(
        h, sK, Kb, Sn, Dn, Rn, (long long)Sn*Rn, (long long)EPE, (long long)Sn*Dn, 1.f, 0, 1, 1);
    bf16_gemm<<<dim3(Dn/64, Sn/128, Bn), 256, 0, stream>>>(
        h, sV, Vb, Sn, Dn, Rn, (long long)Sn*Rn, (long long)EPE, (long long)Sn*Dn, 1.f, 0, 1, 1);

    // ---- 5. causal flash attention (bf16 MFMA) ----
    attn_mfma_kernel<<<dim3(Sn/64, NHn, Bn), 256, 0, stream>>>(Qb, Kb, Vb, Ob);

    // ---- 6. output projection: d_out = O @ Wo^T (split-A bf16) ----
    bf16_gemm<<<dim3(Dn/64, TOK/128, 1), 256, 0, stream>>>(
        Ob, Wo, out, TOK, Dn, Dn, 0LL, 0LL, 0LL, 1.f, 1, 1, 0);

    // ---- 7. knowledge memory: bf16 approx scores + f32 rescore ----
    for (int c = 0; c < 8; ++c) {
        bf16_gemm<<<dim3(NKn/64, 1024/128, 1), 256, 0, stream>>>(
            hm + (size_t)c*1024*Rn, kK, ksc, 1024, NKn, Rn, 0LL, 0LL, 0LL,
            0.0625f, 1, 0, 0);
        mem_rescore_kernel<<<1024, 256, 0, stream>>>(ksc, hm, kK, kV, out, c*1024);
    }
}

// Round 5
// 928.783 us; speedup vs baseline: 3.5032x; 1.2539x over previous
//
#include <hip/hip_runtime.h>

// Problem constants
#define Bn   8
#define Sn   1024
#define Dn   1024
#define Rn   256
#define NHn  16
#define DHn  64
#define NKn  4096
#define TOK  (Bn*Sn)        // 8192 tokens
#define EPE  (Dn*Rn)        // 262144 elements per expert table entry

typedef __attribute__((ext_vector_type(8))) short short8;   // 8 bf16 (4 VGPR)
typedef __attribute__((ext_vector_type(4))) float f32x4;

__device__ inline unsigned short f2bf(float f) {
    union { float f; unsigned u; } v; v.f = f;
    unsigned r = v.u + 0x7fffu + ((v.u >> 16) & 1u);   // round-to-nearest-even
    return (unsigned short)(r >> 16);
}
// split f32 -> hi + lo bf16 (a ~= hi + lo, residual ~2^-18 * a)
__device__ inline void f2bf_split(float f, unsigned short& hi, unsigned short& lo) {
    hi = f2bf(f);
    union { unsigned u; float f; } hv; hv.u = ((unsigned)hi) << 16;
    lo = f2bf(f - hv.f);
}

// ======================================================================
// Split-bf16 MFMA GEMM: C[z] = alpha * A[z](MxK,f32) @ op(B[z]), out f32
// or bf16 (outBF16). splitA/splitB enable double-bf16 passes:
//   acc += Ahi*Bhi  (+ Alo*Bhi if splitA)  (+ Ahi*Blo if splitB)
// Tile 128x64, BK=32, 256 threads = 4 waves (2x2 wave grid, 64x32 each).
// M%128==0, N%64==0, K%32==0.
// ======================================================================
__global__ __launch_bounds__(256) void bf16_gemm(
    const float* __restrict__ A, const float* __restrict__ Bm, float* __restrict__ C,
    int M, int N, int K, long long sA, long long sB, long long sC,
    float alpha, int transB, int splitA, int splitB, int outBF16)
{
    A  += (size_t)blockIdx.z * sA;
    Bm += (size_t)blockIdx.z * sB;
    __shared__ __align__(16) unsigned short AsH[128][40];   // [m][k], 80B rows
    __shared__ __align__(16) unsigned short AsL[128][40];
    __shared__ __align__(16) unsigned short BsH[64][40];    // [n][k]
    __shared__ __align__(16) unsigned short BsL[64][40];
    int tid = threadIdx.x;
    int wave = tid >> 6, lane = tid & 63;
    int lr = lane & 15, lg = lane >> 4;
    int wm = (wave >> 1)*64, wn = (wave & 1)*32;
    int row0 = blockIdx.y*128, col0 = blockIdx.x*64;

    f32x4 acc[4][2];
#pragma unroll
    for (int i = 0; i < 4; ++i)
#pragma unroll
        for (int j = 0; j < 2; ++j) acc[i][j] = (f32x4){0.f,0.f,0.f,0.f};

    for (int k0 = 0; k0 < K; k0 += 32) {
        __syncthreads();
        // ---- stage A tile 128x32 ----
#pragma unroll
        for (int g = 0; g < 2; ++g) {
            int idx = tid + g*256;               // 0..511
            int m2 = idx >> 2, kk = (idx & 3)*8;
            const float* src = A + (size_t)(row0 + m2)*K + k0 + kk;
            float4 f0 = *(const float4*)src;
            float4 f1 = *(const float4*)(src + 4);
            float vals[8] = {f0.x,f0.y,f0.z,f0.w,f1.x,f1.y,f1.z,f1.w};
            short8 wh, wl;
#pragma unroll
            for (int e = 0; e < 8; ++e) {
                unsigned short hi, lo; f2bf_split(vals[e], hi, lo);
                wh[e] = (short)hi; wl[e] = (short)lo;
            }
            *(short8*)&AsH[m2][kk] = wh;
            if (splitA) *(short8*)&AsL[m2][kk] = wl;
        }
        // ---- stage B tile 64x32 ----
        if (transB) {                            // B is N x K (row-major)
            int n2 = tid >> 2, kk = (tid & 3)*8;
            const float* src = Bm + (size_t)(col0 + n2)*K + k0 + kk;
            float4 f0 = *(const float4*)src;
            float4 f1 = *(const float4*)(src + 4);
            float vals[8] = {f0.x,f0.y,f0.z,f0.w,f1.x,f1.y,f1.z,f1.w};
            short8 wh, wl;
#pragma unroll
            for (int e = 0; e < 8; ++e) {
                unsigned short hi, lo; f2bf_split(vals[e], hi, lo);
                wh[e] = (short)hi; wl[e] = (short)lo;
            }
            *(short8*)&BsH[n2][kk] = wh;
            if (splitB) *(short8*)&BsL[n2][kk] = wl;
        } else {                                 // B is K x N: transpose into Bs
            int kk = tid >> 3, n0 = (tid & 7)*8;
            const float* src = Bm + (size_t)(k0 + kk)*N + col0 + n0;
            float4 f0 = *(const float4*)src;
            float4 f1 = *(const float4*)(src + 4);
            float vals[8] = {f0.x,f0.y,f0.z,f0.w,f1.x,f1.y,f1.z,f1.w};
#pragma unroll
            for (int e = 0; e < 8; ++e) {
                unsigned short hi, lo; f2bf_split(vals[e], hi, lo);
                BsH[n0+e][kk] = hi;
                if (splitB) BsL[n0+e][kk] = lo;
            }
        }
        __syncthreads();
        // ---- MFMA passes ----
        short8 afH[4], bfH[2];
#pragma unroll
        for (int i = 0; i < 4; ++i) afH[i] = *(const short8*)&AsH[wm + i*16 + lr][lg*8];
#pragma unroll
        for (int j = 0; j < 2; ++j) bfH[j] = *(const short8*)&BsH[wn + j*16 + lr][lg*8];
#pragma unroll
        for (int i = 0; i < 4; ++i)
#pragma unroll
            for (int j = 0; j < 2; ++j)
                acc[i][j] = __builtin_amdgcn_mfma_f32_16x16x32_bf16(afH[i], bfH[j], acc[i][j], 0, 0, 0);
        if (splitA) {
            short8 afL[4];
#pragma unroll
            for (int i = 0; i < 4; ++i) afL[i] = *(const short8*)&AsL[wm + i*16 + lr][lg*8];
#pragma unroll
            for (int i = 0; i < 4; ++i)
#pragma unroll
                for (int j = 0; j < 2; ++j)
                    acc[i][j] = __builtin_amdgcn_mfma_f32_16x16x32_bf16(afL[i], bfH[j], acc[i][j], 0, 0, 0);
        }
        if (splitB) {
            short8 bfL[2];
#pragma unroll
            for (int j = 0; j < 2; ++j) bfL[j] = *(const short8*)&BsL[wn + j*16 + lr][lg*8];
#pragma unroll
            for (int i = 0; i < 4; ++i)
#pragma unroll
                for (int j = 0; j < 2; ++j)
                    acc[i][j] = __builtin_amdgcn_mfma_f32_16x16x32_bf16(afH[i], bfL[j], acc[i][j], 0, 0, 0);
        }
    }
    // ---- epilogue ----
    size_t zoff = (size_t)blockIdx.z * sC;
    if (outBF16) {
        unsigned short* Cb = (unsigned short*)C + zoff;
#pragma unroll
        for (int i = 0; i < 4; ++i)
#pragma unroll
            for (int j = 0; j < 2; ++j)
#pragma unroll
                for (int r = 0; r < 4; ++r)
                    Cb[(size_t)(row0 + wm + i*16 + lg*4 + r)*N + col0 + wn + j*16 + lr]
                        = f2bf(acc[i][j][r] * alpha);
    } else {
        float* Cf = C + zoff;
#pragma unroll
        for (int i = 0; i < 4; ++i)
#pragma unroll
            for (int j = 0; j < 2; ++j)
#pragma unroll
                for (int r = 0; r < 4; ++r)
                    Cf[(size_t)(row0 + wm + i*16 + lg*4 + r)*N + col0 + wn + j*16 + lr]
                        = acc[i][j][r] * alpha;
    }
}

// ======================================================================
// Router post: softmax(logits)*importance, partial-sum over 256-token
// chunks. logits [8192][320]; partial [5][8][4][64].
// ======================================================================
__global__ __launch_bounds__(256) void router_post(
    const float* __restrict__ logits, const float* __restrict__ imp,
    float* __restrict__ partial)
{
    int blk = blockIdx.x;                 // 0..159
    int chunk = blk & 3, b = (blk >> 2) & 7, r = blk >> 5;
    int tid = threadIdx.x, lane = tid & 63, wv = tid >> 6;
    float acc = 0.f;
    for (int i = wv; i < 256; i += 4) {
        int t = b*1024 + chunk*256 + i;
        float lgv = logits[(size_t)t*320 + r*64 + lane];
        float mx = lgv;
        for (int off = 32; off >= 1; off >>= 1) mx = fmaxf(mx, __shfl_xor(mx, off));
        float e = __expf(lgv - mx);
        float s = e;
        for (int off = 32; off >= 1; off >>= 1) s += __shfl_xor(s, off);
        acc += imp[t] * e / s;
    }
    __shared__ float red[4][64];
    red[wv][lane] = acc;
    __syncthreads();
    if (tid < 64)
        partial[((size_t)(r*8 + b)*4 + chunk)*64 + tid]
            = red[0][tid] + red[1][tid] + red[2][tid] + red[3][tid];
}

// Normalize, top-k (k=16 for routers 0,4; k=8 for 1,2,3), renormalize.
__global__ void topk_router(const float* __restrict__ partial,
                            float* __restrict__ tw, int* __restrict__ ti)
{
    int rb = blockIdx.x;           // r*8+b
    int r  = rb >> 3;
    int lane = threadIdx.x;        // 64 threads = 1 wave
    float v = partial[((size_t)rb*4 + 0)*64 + lane] + partial[((size_t)rb*4 + 1)*64 + lane]
            + partial[((size_t)rb*4 + 2)*64 + lane] + partial[((size_t)rb*4 + 3)*64 + lane];
    float s = v;
    for (int off = 32; off >= 1; off >>= 1) s += __shfl_xor(s, off);
    v = v / (s + 1e-8f);
    int k = (r == 0 || r == 4) ? 16 : 8;
    __shared__ float tv[16];
    __shared__ int   tix[16];
    float cur = v;
    for (int it = 0; it < k; ++it) {
        float bv = cur; int bi = lane;
        for (int off = 32; off >= 1; off >>= 1) {
            float ov = __shfl_xor(bv, off);
            int   oi = __shfl_xor(bi, off);
            if (ov > bv || (ov == bv && oi < bi)) { bv = ov; bi = oi; }
        }
        if (bi == lane) cur = -1e30f;
        if (lane == 0) { tv[it] = bv; tix[it] = bi; }
    }
    __syncthreads();
    float s2 = 0.f;
    for (int i = 0; i < k; ++i) s2 += tv[i];
    float inv = 1.f / (s2 + 1e-8f);
    if (lane < k) {
        tw[(size_t)rb*16 + lane] = tv[lane] * inv;
        ti[(size_t)rb*16 + lane] = tix[lane];
    }
}

// out[b][e] = sum_i tw[b][i] * table[ti[b][i]][e]
__global__ __launch_bounds__(256) void combine_kernel(
    const float* __restrict__ table, const float* __restrict__ tw,
    const int* __restrict__ ti, float* __restrict__ out, int k)
{
    int b = blockIdx.y;
    size_t e = ((size_t)blockIdx.x*256 + threadIdx.x)*4;
    float4 acc = {0.f, 0.f, 0.f, 0.f};
    for (int i = 0; i < k; ++i) {
        float w = tw[b*16 + i];
        int  idx = ti[b*16 + i];
        float4 t = *(const float4*)&table[(size_t)idx*EPE + e];
        acc.x += w*t.x; acc.y += w*t.y; acc.z += w*t.z; acc.w += w*t.w;
    }
    *(float4*)&out[(size_t)b*EPE + e] = acc;
}

// ======================================================================
// MFMA bf16 flash attention, bf16 inputs, paired q-tiles for balance.
// Block = 4 waves; block a handles q-tiles a and 15-a (17 k-iters total).
// ======================================================================
#define PADK 72

__global__ __launch_bounds__(256) void attn_mfma_kernel(
    const unsigned short* __restrict__ Q, const unsigned short* __restrict__ K,
    const unsigned short* __restrict__ V, float* __restrict__ O)
{
    int aa = blockIdx.x, hh = blockIdx.y, b = blockIdx.z;
    int tid  = threadIdx.x;
    int wave = tid >> 6, lane = tid & 63;
    int lr = lane & 15, lg = lane >> 4;

    __shared__ __align__(16) unsigned short Kt[64][PADK];
    __shared__ __align__(16) unsigned short Vt[64][PADK];   // Vt[d][kv]
    __shared__ __align__(16) unsigned short Pt[64][PADK];

    for (int ph = 0; ph < 2; ++ph) {
        int qt = ph ? (15 - aa) : aa;
        const unsigned short* Qrow =
            Q + ((size_t)b*Sn + (size_t)qt*64 + wave*16 + lr)*Dn + hh*64;
        short8 qf0 = *(const short8*)&Qrow[lg*8];
        short8 qf1 = *(const short8*)&Qrow[32 + lg*8];

        f32x4 o[4];
#pragma unroll
        for (int ct = 0; ct < 4; ++ct) o[ct] = (f32x4){0.f,0.f,0.f,0.f};
        float m[4]  = {-1e30f,-1e30f,-1e30f,-1e30f};
        float l[4]  = {0.f,0.f,0.f,0.f};

        for (int kt = 0; kt <= qt; ++kt) {
            __syncthreads();   // prior LDS reads done
            const unsigned short* Kb = K + ((size_t)b*Sn + (size_t)kt*64)*Dn + hh*64;
            const unsigned short* Vb = V + ((size_t)b*Sn + (size_t)kt*64)*Dn + hh*64;
            // ---- stage K[kv][d] (bf16 direct copy) ----
#pragma unroll
            for (int it2 = 0; it2 < 2; ++it2) {
                int idx = tid + it2*256;               // 0..511
                int kv = idx >> 3, d0 = (idx & 7)*8;
                *(short8*)&Kt[kv][d0] = *(const short8*)&Kb[(size_t)kv*Dn + d0];
            }
            // ---- stage V transposed: Vt[d][kv] ----
#pragma unroll
            for (int it2 = 0; it2 < 2; ++it2) {
                int idx = tid + it2*256;
                int kv = idx & 63, d0 = (idx >> 6)*8;
                short8 w = *(const short8*)&Vb[(size_t)kv*Dn + d0];
#pragma unroll
                for (int e = 0; e < 8; ++e) Vt[d0+e][kv] = (unsigned short)w[e];
            }
            __syncthreads();

            // ---- S = Q K^T ----
            f32x4 s[4];
#pragma unroll
            for (int ct = 0; ct < 4; ++ct) {
                s[ct] = (f32x4){0.f,0.f,0.f,0.f};
                short8 k0 = *(const short8*)&Kt[ct*16 + lr][lg*8];
                short8 k1 = *(const short8*)&Kt[ct*16 + lr][32 + lg*8];
                s[ct] = __builtin_amdgcn_mfma_f32_16x16x32_bf16(qf0, k0, s[ct], 0, 0, 0);
                s[ct] = __builtin_amdgcn_mfma_f32_16x16x32_bf16(qf1, k1, s[ct], 0, 0, 0);
            }

            float mx[4] = {-1e30f,-1e30f,-1e30f,-1e30f};
            int qg0 = qt*64 + wave*16 + lg*4;
#pragma unroll
            for (int ct = 0; ct < 4; ++ct) {
                int kvg = kt*64 + ct*16 + lr;
#pragma unroll
                for (int r = 0; r < 4; ++r) {
                    float v = s[ct][r] * 0.125f;
                    if (kt == qt && kvg > qg0 + r) v = -1e30f;
                    s[ct][r] = v;
                    mx[r] = fmaxf(mx[r], v);
                }
            }
#pragma unroll
            for (int r = 0; r < 4; ++r) {
                mx[r] = fmaxf(mx[r], __shfl_xor(mx[r], 1));
                mx[r] = fmaxf(mx[r], __shfl_xor(mx[r], 2));
                mx[r] = fmaxf(mx[r], __shfl_xor(mx[r], 4));
                mx[r] = fmaxf(mx[r], __shfl_xor(mx[r], 8));
            }

            float corr[4], ps[4] = {0.f,0.f,0.f,0.f};
#pragma unroll
            for (int r = 0; r < 4; ++r) {
                float mn = fmaxf(m[r], mx[r]);
                corr[r] = __expf(m[r] - mn);
                m[r] = mn;
            }
#pragma unroll
            for (int ct = 0; ct < 4; ++ct)
#pragma unroll
                for (int r = 0; r < 4; ++r) {
                    float e = __expf(s[ct][r] - m[r]);
                    s[ct][r] = e;
                    ps[r] += e;
                }
#pragma unroll
            for (int r = 0; r < 4; ++r) {
                ps[r] += __shfl_xor(ps[r], 1);
                ps[r] += __shfl_xor(ps[r], 2);
                ps[r] += __shfl_xor(ps[r], 4);
                ps[r] += __shfl_xor(ps[r], 8);
                l[r] = l[r]*corr[r] + ps[r];
#pragma unroll
                for (int ct = 0; ct < 4; ++ct) o[ct][r] *= corr[r];
            }

            // ---- P (D-layout) -> LDS bf16 ----
#pragma unroll
            for (int ct = 0; ct < 4; ++ct)
#pragma unroll
                for (int r = 0; r < 4; ++r)
                    Pt[wave*16 + lg*4 + r][ct*16 + lr] = f2bf(s[ct][r]);
            __syncthreads();

            short8 pa0 = *(const short8*)&Pt[wave*16 + lr][lg*8];
            short8 pa1 = *(const short8*)&Pt[wave*16 + lr][32 + lg*8];
#pragma unroll
            for (int ct = 0; ct < 4; ++ct) {
                short8 v0 = *(const short8*)&Vt[ct*16 + lr][lg*8];
                short8 v1 = *(const short8*)&Vt[ct*16 + lr][32 + lg*8];
                o[ct] = __builtin_amdgcn_mfma_f32_16x16x32_bf16(pa0, v0, o[ct], 0, 0, 0);
                o[ct] = __builtin_amdgcn_mfma_f32_16x16x32_bf16(pa1, v1, o[ct], 0, 0, 0);
            }
        }

        float* Op = O + ((size_t)b*Sn + (size_t)qt*64 + wave*16 + lg*4)*Dn + hh*64 + lr;
#pragma unroll
        for (int r = 0; r < 4; ++r) {
            float inv = 1.f / l[r];
#pragma unroll
            for (int ct = 0; ct < 4; ++ct)
                Op[(size_t)r*Dn + ct*16] = o[ct][r] * inv;
        }
    }
}

// ======================================================================
// Knowledge memory, wave-per-token: approx top-16 scan (shfl-only),
// f32 rescore of 16 candidates, exact top-8 + softmax + V gather-add.
// Block = 4 waves = 4 tokens.
// ======================================================================
__global__ __launch_bounds__(256) void mem_topk_wave(
    const float* __restrict__ ksc,   // [4096][4096] chunk-local approx scores
    const float* __restrict__ hm,    // [8192][256] f32
    const float* __restrict__ kK,    // [4096][256]
    const float* __restrict__ kV,    // [4096][1024]
    float* __restrict__ out, int tok0)
{
    int wave = threadIdx.x >> 6, lane = threadIdx.x & 63;
    int t = blockIdx.x*4 + wave;            // chunk-local token
    const float* row = ksc + (size_t)t*NKn;

    // lane owns 64 contiguous scores: indices lane*64 .. lane*64+63
    float v[64];
#pragma unroll
    for (int j4 = 0; j4 < 16; ++j4) {
        float4 f = *(const float4*)&row[lane*64 + j4*4];
        v[j4*4+0]=f.x; v[j4*4+1]=f.y; v[j4*4+2]=f.z; v[j4*4+3]=f.w;
    }

    __shared__ float s_cs[4][16];
    __shared__ int   s_tix[4][16];

    // ---- wave top-16 (approx scores), ties -> lowest index ----
    for (int it = 0; it < 16; ++it) {
        float bv = -3e38f; int bi = 0x7fffffff;
#pragma unroll
        for (int j = 0; j < 64; ++j) {
            int n = lane*64 + j;
            if (v[j] > bv || (v[j] == bv && n < bi)) { bv = v[j]; bi = n; }
        }
#pragma unroll
        for (int off = 32; off >= 1; off >>= 1) {
            float ov = __shfl_xor(bv, off);
            int   oi = __shfl_xor(bi, off);
            if (ov > bv || (ov == bv && oi < bi)) { bv = ov; bi = oi; }
        }
        if (lane == 0) s_tix[wave][it] = bi;
        // mark used (static reg indices)
#pragma unroll
        for (int j = 0; j < 64; ++j)
            if (lane*64 + j == bi) v[j] = -3e38f;
    }

    // ---- f32 rescore: lane = cand*4 + quarter; 64 elems each ----
    int c = lane >> 2, q = lane & 3;
    int kidx = s_tix[wave][c];
    const float* kr = kK + (size_t)kidx*Rn;
    const float* hr = hm + (size_t)(tok0 + t)*Rn;
    float d = 0.f;
#pragma unroll
    for (int j4 = 0; j4 < 16; ++j4) {
        float4 a  = *(const float4*)&hr[q*64 + j4*4];
        float4 bb = *(const float4*)&kr[q*64 + j4*4];
        d += a.x*bb.x + a.y*bb.y + a.z*bb.z + a.w*bb.w;
    }
    d += __shfl_xor(d, 1);
    d += __shfl_xor(d, 2);
    if (q == 0) s_cs[wave][c] = d * 0.0625f;      // 1/sqrt(256)

    // ---- exact top-8 of 16 (in-wave; all lanes learn all winners) ----
    float cv = (lane < 16) ? s_cs[wave][lane] : -3e38f;
    int   ck = (lane < 16) ? s_tix[wave][lane] : 0x7fffffff;
    float sv[8]; int si[8];
#pragma unroll
    for (int it = 0; it < 8; ++it) {
        float bv = cv; int bk = ck;
#pragma unroll
        for (int off = 32; off >= 1; off >>= 1) {
            float ov = __shfl_xor(bv, off);
            int   ok = __shfl_xor(bk, off);
            if (ov > bv || (ov == bv && ok < bk)) { bv = ov; bk = ok; }
        }
        sv[it] = bv; si[it] = bk;
        if (ck == bk) cv = -3e38f;     // knowledge indices distinct
    }

    // ---- softmax over 8 + weighted V gather, add into out ----
    float mxv = sv[0];
#pragma unroll
    for (int kx = 1; kx < 8; ++kx) mxv = fmaxf(mxv, sv[kx]);
    float p[8]; float sum = 0.f;
#pragma unroll
    for (int kx = 0; kx < 8; ++kx) { p[kx] = __expf(sv[kx] - mxv); sum += p[kx]; }
    float invs = 1.f / sum;
    float4 acc0 = {0,0,0,0}, acc1 = {0,0,0,0}, acc2 = {0,0,0,0}, acc3 = {0,0,0,0};
#pragma unroll
    for (int kx = 0; kx < 8; ++kx) {
        float pk = p[kx]*invs;
        const float* vp = kV + (size_t)si[kx]*Dn + lane*16;
        float4 v0 = *(const float4*)(vp + 0);
        float4 v1 = *(const float4*)(vp + 4);
        float4 v2 = *(const float4*)(vp + 8);
        float4 v3 = *(const float4*)(vp + 12);
        acc0.x += pk*v0.x; acc0.y += pk*v0.y; acc0.z += pk*v0.z; acc0.w += pk*v0.w;
        acc1.x += pk*v1.x; acc1.y += pk*v1.y; acc1.z += pk*v1.z; acc1.w += pk*v1.w;
        acc2.x += pk*v2.x; acc2.y += pk*v2.y; acc2.z += pk*v2.z; acc2.w += pk*v2.w;
        acc3.x += pk*v3.x; acc3.y += pk*v3.y; acc3.z += pk*v3.z; acc3.w += pk*v3.w;
    }
    float* op = out + (size_t)(tok0 + t)*Dn + lane*16;
    float4 c0 = *(const float4*)(op + 0);
    float4 c1 = *(const float4*)(op + 4);
    float4 c2 = *(const float4*)(op + 8);
    float4 c3 = *(const float4*)(op + 12);
    c0.x+=acc0.x; c0.y+=acc0.y; c0.z+=acc0.z; c0.w+=acc0.w;
    c1.x+=acc1.x; c1.y+=acc1.y; c1.z+=acc1.z; c1.w+=acc1.w;
    c2.x+=acc2.x; c2.y+=acc2.y; c2.z+=acc2.z; c2.w+=acc2.w;
    c3.x+=acc3.x; c3.y+=acc3.y; c3.z+=acc3.z; c3.w+=acc3.w;
    *(float4*)(op + 0)  = c0;
    *(float4*)(op + 4)  = c1;
    *(float4*)(op + 8)  = c2;
    *(float4*)(op + 12) = c3;
}

// ======================================================================
extern "C" void kernel_launch(void* const* d_in, const int* in_sizes, int n_in,
                              void* d_out, int out_size, void* d_ws, size_t ws_size,
                              hipStream_t stream)
{
    const float* x          = (const float*)d_in[0];
    const float* imp        = (const float*)d_in[1];
    const float* compress_w = (const float*)d_in[2];
    const float* expQ_w     = (const float*)d_in[3];
    const float* expK_w     = (const float*)d_in[4];
    const float* expV_w     = (const float*)d_in[5];
    const float* memory_w   = (const float*)d_in[6];
    const float* neurons    = (const float*)d_in[7];   // [64, D, R]
    const float* pool       = (const float*)d_in[8];   // [64, R, D]
    const float* kK         = (const float*)d_in[9];   // [4096, R]
    const float* kV         = (const float*)d_in[10];  // [4096, D]
    const float* Wo         = (const float*)d_in[11];  // [D, D]
    float* out = (float*)d_out;

    // ---- workspace layout (~150 MB) ----
    char* ws = (char*)d_ws;
    size_t off = 0;
    auto alloc = [&](size_t bytes) {
        size_t o = off; off = (off + bytes + 255) & ~(size_t)255; return (void*)(ws + o);
    };
    float* wcat    = (float*)alloc((size_t)5*64*Dn*4);     // concat router weights
    float* logits  = (float*)alloc((size_t)TOK*320*4);
    float* partial = (float*)alloc((size_t)40*4*64*4);
    float* tw      = (float*)alloc((size_t)5*Bn*16*4);
    int*   ti      = (int*)  alloc((size_t)5*Bn*16*4);
    float* sh_c = (float*)alloc((size_t)Bn*EPE*4);
    float* sh_m = (float*)alloc((size_t)Bn*EPE*4);
    float* sQ   = (float*)alloc((size_t)Bn*EPE*4);
    float* sK   = (float*)alloc((size_t)Bn*EPE*4);
    float* sV   = (float*)alloc((size_t)Bn*EPE*4);
    float* h    = (float*)alloc((size_t)Bn*Sn*Rn*4);
    float* hm   = (float*)alloc((size_t)Bn*Sn*Rn*4);
    unsigned short* Qb16 = (unsigned short*)alloc((size_t)Bn*Sn*Dn*2);
    unsigned short* Kb16 = (unsigned short*)alloc((size_t)Bn*Sn*Dn*2);
    unsigned short* Vb16 = (unsigned short*)alloc((size_t)Bn*Sn*Dn*2);
    float* Ob   = (float*)alloc((size_t)Bn*Sn*Dn*4);
    // ksc (64 MB per chunk) aliases Qb16..Ob (80 MB), all dead post-Wo
    float* ksc = (float*)Qb16;
    (void)ws_size; (void)in_sizes; (void)n_in; (void)out_size;

    // ---- 1. routers: concat weights, one split-bf16 GEMM, fused post ----
    hipMemcpyAsync(wcat + 0*64*Dn, compress_w, (size_t)64*Dn*4, hipMemcpyDeviceToDevice, stream);
    hipMemcpyAsync(wcat + 1*64*Dn, expQ_w,     (size_t)64*Dn*4, hipMemcpyDeviceToDevice, stream);
    hipMemcpyAsync(wcat + 2*64*Dn, expK_w,     (size_t)64*Dn*4, hipMemcpyDeviceToDevice, stream);
    hipMemcpyAsync(wcat + 3*64*Dn, expV_w,     (size_t)64*Dn*4, hipMemcpyDeviceToDevice, stream);
    hipMemcpyAsync(wcat + 4*64*Dn, memory_w,   (size_t)64*Dn*4, hipMemcpyDeviceToDevice, stream);
    bf16_gemm<<<dim3(5, 64, 1), 256, 0, stream>>>(
        x, wcat, logits, TOK, 320, Dn, 0LL, 0LL, 0LL, 1.f, 1, 1, 1, 0);
    router_post<<<160, 256, 0, stream>>>(logits, imp, partial);
    topk_router<<<40, 64, 0, stream>>>(partial, tw, ti);

    // ---- 2. expert combines (0=c,1=Q,2=K,3=V,4=mem) ----
    dim3 cgrid(EPE/1024, Bn);
    combine_kernel<<<cgrid, 256, 0, stream>>>(neurons, tw + 0*128, ti + 0*128, sh_c, 16);
    combine_kernel<<<cgrid, 256, 0, stream>>>(pool,    tw + 1*128, ti + 1*128, sQ,   8);
    combine_kernel<<<cgrid, 256, 0, stream>>>(pool,    tw + 2*128, ti + 2*128, sK,   8);
    combine_kernel<<<cgrid, 256, 0, stream>>>(pool,    tw + 3*128, ti + 3*128, sV,   8);
    combine_kernel<<<cgrid, 256, 0, stream>>>(neurons, tw + 4*128, ti + 4*128, sh_m, 16);

    // ---- 3. h = x @ sh_c ; hm = x @ sh_m  (split-bf16, f32-accurate) ----
    bf16_gemm<<<dim3(Rn/64, Sn/128, Bn), 256, 0, stream>>>(
        x, sh_c, h, Sn, Rn, Dn, (long long)Sn*Dn, (long long)EPE, (long long)Sn*Rn, 1.f, 0, 1, 1, 0);
    bf16_gemm<<<dim3(Rn/64, Sn/128, Bn), 256, 0, stream>>>(
        x, sh_m, hm, Sn, Rn, Dn, (long long)Sn*Dn, (long long)EPE, (long long)Sn*Rn, 1.f, 0, 1, 1, 0);

    // ---- 4. Q/K/V = h @ sharedX (split-bf16, bf16 output) ----
    bf16_gemm<<<dim3(Dn/64, Sn/128, Bn), 256, 0, stream>>>(
        h, sQ, (float*)Qb16, Sn, Dn, Rn, (long long)Sn*Rn, (long long)EPE, (long long)Sn*Dn, 1.f, 0, 1, 1, 1);
    bf16_gemm<<<dim3(Dn/64, Sn/128, Bn), 256, 0, stream>>>(
        h, sK, (float*)Kb16, Sn, Dn, Rn, (long long)Sn*Rn, (long long)EPE, (long long)Sn*Dn, 1.f, 0, 1, 1, 1);
    bf16_gemm<<<dim3(Dn/64, Sn/128, Bn), 256, 0, stream>>>(
        h, sV, (float*)Vb16, Sn, Dn, Rn, (long long)Sn*Rn, (long long)EPE, (long long)Sn*Dn, 1.f, 0, 1, 1, 1);

    // ---- 5. causal flash attention (bf16 in, paired q-tiles) ----
    attn_mfma_kernel<<<dim3(8, NHn, Bn), 256, 0, stream>>>(Qb16, Kb16, Vb16, Ob);

    // ---- 6. output projection: d_out = O @ Wo^T (split-A bf16) ----
    bf16_gemm<<<dim3(Dn/64, TOK/128, 1), 256, 0, stream>>>(
        Ob, Wo, out, TOK, Dn, Dn, 0LL, 0LL, 0LL, 1.f, 1, 1, 0, 0);

    // ---- 7. knowledge memory: 2 chunks of 4096 tokens ----
    for (int c = 0; c < 2; ++c) {
        bf16_gemm<<<dim3(NKn/64, 4096/128, 1), 256, 0, stream>>>(
            hm + (size_t)c*4096*Rn, kK, ksc, 4096, NKn, Rn, 0LL, 0LL, 0LL,
            0.0625f, 1, 0, 0, 0);
        mem_topk_wave<<<1024, 256, 0, stream>>>(ksc, hm, kK, kV, out, c*4096);
    }
}

// Round 6
// 762.279 us; speedup vs baseline: 4.2684x; 1.2184x over previous
//
#include <hip/hip_runtime.h>

// Problem constants
#define Bn   8
#define Sn   1024
#define Dn   1024
#define Rn   256
#define NHn  16
#define DHn  64
#define NKn  4096
#define TOK  (Bn*Sn)        // 8192 tokens
#define EPE  (Dn*Rn)        // 262144 elements per expert table entry

typedef __attribute__((ext_vector_type(8))) short short8;   // 8 bf16 (4 VGPR)
typedef __attribute__((ext_vector_type(4))) float f32x4;

__device__ inline unsigned short f2bf(float f) {
    union { float f; unsigned u; } v; v.f = f;
    unsigned r = v.u + 0x7fffu + ((v.u >> 16) & 1u);   // round-to-nearest-even
    return (unsigned short)(r >> 16);
}
// split f32 -> hi + lo bf16 (a ~= hi + lo, residual ~2^-18 * a)
__device__ inline void f2bf_split(float f, unsigned short& hi, unsigned short& lo) {
    hi = f2bf(f);
    union { unsigned u; float f; } hv; hv.u = ((unsigned)hi) << 16;
    lo = f2bf(f - hv.f);
}

// ======================================================================
// Split-bf16 MFMA GEMM: C[z] = alpha * A[z](MxK,f32) @ op(B[z]), out f32
// or bf16 (outBF16). splitA/splitB enable double-bf16 passes:
//   acc += Ahi*Bhi  (+ Alo*Bhi if splitA)  (+ Ahi*Blo if splitB)
// Tile 128x64, BK=32, 256 threads = 4 waves (2x2 wave grid, 64x32 each).
// M%128==0, N%64==0, K%32==0.
// ======================================================================
__global__ __launch_bounds__(256) void bf16_gemm(
    const float* __restrict__ A, const float* __restrict__ Bm, float* __restrict__ C,
    int M, int N, int K, long long sA, long long sB, long long sC,
    float alpha, int transB, int splitA, int splitB, int outBF16)
{
    A  += (size_t)blockIdx.z * sA;
    Bm += (size_t)blockIdx.z * sB;
    __shared__ __align__(16) unsigned short AsH[128][40];   // [m][k], 80B rows
    __shared__ __align__(16) unsigned short AsL[128][40];
    __shared__ __align__(16) unsigned short BsH[64][40];    // [n][k]
    __shared__ __align__(16) unsigned short BsL[64][40];
    int tid = threadIdx.x;
    int wave = tid >> 6, lane = tid & 63;
    int lr = lane & 15, lg = lane >> 4;
    int wm = (wave >> 1)*64, wn = (wave & 1)*32;
    int row0 = blockIdx.y*128, col0 = blockIdx.x*64;

    f32x4 acc[4][2];
#pragma unroll
    for (int i = 0; i < 4; ++i)
#pragma unroll
        for (int j = 0; j < 2; ++j) acc[i][j] = (f32x4){0.f,0.f,0.f,0.f};

    for (int k0 = 0; k0 < K; k0 += 32) {
        __syncthreads();
        // ---- stage A tile 128x32 ----
#pragma unroll
        for (int g = 0; g < 2; ++g) {
            int idx = tid + g*256;               // 0..511
            int m2 = idx >> 2, kk = (idx & 3)*8;
            const float* src = A + (size_t)(row0 + m2)*K + k0 + kk;
            float4 f0 = *(const float4*)src;
            float4 f1 = *(const float4*)(src + 4);
            float vals[8] = {f0.x,f0.y,f0.z,f0.w,f1.x,f1.y,f1.z,f1.w};
            short8 wh, wl;
#pragma unroll
            for (int e = 0; e < 8; ++e) {
                unsigned short hi, lo; f2bf_split(vals[e], hi, lo);
                wh[e] = (short)hi; wl[e] = (short)lo;
            }
            *(short8*)&AsH[m2][kk] = wh;
            if (splitA) *(short8*)&AsL[m2][kk] = wl;
        }
        // ---- stage B tile 64x32 ----
        if (transB) {                            // B is N x K (row-major)
            int n2 = tid >> 2, kk = (tid & 3)*8;
            const float* src = Bm + (size_t)(col0 + n2)*K + k0 + kk;
            float4 f0 = *(const float4*)src;
            float4 f1 = *(const float4*)(src + 4);
            float vals[8] = {f0.x,f0.y,f0.z,f0.w,f1.x,f1.y,f1.z,f1.w};
            short8 wh, wl;
#pragma unroll
            for (int e = 0; e < 8; ++e) {
                unsigned short hi, lo; f2bf_split(vals[e], hi, lo);
                wh[e] = (short)hi; wl[e] = (short)lo;
            }
            *(short8*)&BsH[n2][kk] = wh;
            if (splitB) *(short8*)&BsL[n2][kk] = wl;
        } else {                                 // B is K x N: transpose into Bs
            int kk = tid >> 3, n0 = (tid & 7)*8;
            const float* src = Bm + (size_t)(k0 + kk)*N + col0 + n0;
            float4 f0 = *(const float4*)src;
            float4 f1 = *(const float4*)(src + 4);
            float vals[8] = {f0.x,f0.y,f0.z,f0.w,f1.x,f1.y,f1.z,f1.w};
#pragma unroll
            for (int e = 0; e < 8; ++e) {
                unsigned short hi, lo; f2bf_split(vals[e], hi, lo);
                BsH[n0+e][kk] = hi;
                if (splitB) BsL[n0+e][kk] = lo;
            }
        }
        __syncthreads();
        // ---- MFMA passes ----
        short8 afH[4], bfH[2];
#pragma unroll
        for (int i = 0; i < 4; ++i) afH[i] = *(const short8*)&AsH[wm + i*16 + lr][lg*8];
#pragma unroll
        for (int j = 0; j < 2; ++j) bfH[j] = *(const short8*)&BsH[wn + j*16 + lr][lg*8];
#pragma unroll
        for (int i = 0; i < 4; ++i)
#pragma unroll
            for (int j = 0; j < 2; ++j)
                acc[i][j] = __builtin_amdgcn_mfma_f32_16x16x32_bf16(afH[i], bfH[j], acc[i][j], 0, 0, 0);
        if (splitA) {
            short8 afL[4];
#pragma unroll
            for (int i = 0; i < 4; ++i) afL[i] = *(const short8*)&AsL[wm + i*16 + lr][lg*8];
#pragma unroll
            for (int i = 0; i < 4; ++i)
#pragma unroll
                for (int j = 0; j < 2; ++j)
                    acc[i][j] = __builtin_amdgcn_mfma_f32_16x16x32_bf16(afL[i], bfH[j], acc[i][j], 0, 0, 0);
        }
        if (splitB) {
            short8 bfL[2];
#pragma unroll
            for (int j = 0; j < 2; ++j) bfL[j] = *(const short8*)&BsL[wn + j*16 + lr][lg*8];
#pragma unroll
            for (int i = 0; i < 4; ++i)
#pragma unroll
                for (int j = 0; j < 2; ++j)
                    acc[i][j] = __builtin_amdgcn_mfma_f32_16x16x32_bf16(afH[i], bfL[j], acc[i][j], 0, 0, 0);
        }
    }
    // ---- epilogue ----
    size_t zoff = (size_t)blockIdx.z * sC;
    if (outBF16) {
        unsigned short* Cb = (unsigned short*)C + zoff;
#pragma unroll
        for (int i = 0; i < 4; ++i)
#pragma unroll
            for (int j = 0; j < 2; ++j)
#pragma unroll
                for (int r = 0; r < 4; ++r)
                    Cb[(size_t)(row0 + wm + i*16 + lg*4 + r)*N + col0 + wn + j*16 + lr]
                        = f2bf(acc[i][j][r] * alpha);
    } else {
        float* Cf = C + zoff;
#pragma unroll
        for (int i = 0; i < 4; ++i)
#pragma unroll
            for (int j = 0; j < 2; ++j)
#pragma unroll
                for (int r = 0; r < 4; ++r)
                    Cf[(size_t)(row0 + wm + i*16 + lg*4 + r)*N + col0 + wn + j*16 + lr]
                        = acc[i][j][r] * alpha;
    }
}

// ======================================================================
// Router post: softmax(logits)*importance, partial-sum over 256-token
// chunks. logits [8192][320]; partial [5][8][4][64].
// ======================================================================
__global__ __launch_bounds__(256) void router_post(
    const float* __restrict__ logits, const float* __restrict__ imp,
    float* __restrict__ partial)
{
    int blk = blockIdx.x;                 // 0..159
    int chunk = blk & 3, b = (blk >> 2) & 7, r = blk >> 5;
    int tid = threadIdx.x, lane = tid & 63, wv = tid >> 6;
    float acc = 0.f;
    for (int i = wv; i < 256; i += 4) {
        int t = b*1024 + chunk*256 + i;
        float lgv = logits[(size_t)t*320 + r*64 + lane];
        float mx = lgv;
        for (int off = 32; off >= 1; off >>= 1) mx = fmaxf(mx, __shfl_xor(mx, off));
        float e = __expf(lgv - mx);
        float s = e;
        for (int off = 32; off >= 1; off >>= 1) s += __shfl_xor(s, off);
        acc += imp[t] * e / s;
    }
    __shared__ float red[4][64];
    red[wv][lane] = acc;
    __syncthreads();
    if (tid < 64)
        partial[((size_t)(r*8 + b)*4 + chunk)*64 + tid]
            = red[0][tid] + red[1][tid] + red[2][tid] + red[3][tid];
}

// Normalize, top-k (k=16 for routers 0,4; k=8 for 1,2,3), renormalize.
__global__ void topk_router(const float* __restrict__ partial,
                            float* __restrict__ tw, int* __restrict__ ti)
{
    int rb = blockIdx.x;           // r*8+b
    int r  = rb >> 3;
    int lane = threadIdx.x;        // 64 threads = 1 wave
    float v = partial[((size_t)rb*4 + 0)*64 + lane] + partial[((size_t)rb*4 + 1)*64 + lane]
            + partial[((size_t)rb*4 + 2)*64 + lane] + partial[((size_t)rb*4 + 3)*64 + lane];
    float s = v;
    for (int off = 32; off >= 1; off >>= 1) s += __shfl_xor(s, off);
    v = v / (s + 1e-8f);
    int k = (r == 0 || r == 4) ? 16 : 8;
    __shared__ float tv[16];
    __shared__ int   tix[16];
    float cur = v;
    for (int it = 0; it < k; ++it) {
        float bv = cur; int bi = lane;
        for (int off = 32; off >= 1; off >>= 1) {
            float ov = __shfl_xor(bv, off);
            int   oi = __shfl_xor(bi, off);
            if (ov > bv || (ov == bv && oi < bi)) { bv = ov; bi = oi; }
        }
        if (bi == lane) cur = -1e30f;
        if (lane == 0) { tv[it] = bv; tix[it] = bi; }
    }
    __syncthreads();
    float s2 = 0.f;
    for (int i = 0; i < k; ++i) s2 += tv[i];
    float inv = 1.f / (s2 + 1e-8f);
    if (lane < k) {
        tw[(size_t)rb*16 + lane] = tv[lane] * inv;
        ti[(size_t)rb*16 + lane] = tix[lane];
    }
}

// out[b][e] = sum_i tw[b][i] * table[ti[b][i]][e]
__global__ __launch_bounds__(256) void combine_kernel(
    const float* __restrict__ table, const float* __restrict__ tw,
    const int* __restrict__ ti, float* __restrict__ out, int k)
{
    int b = blockIdx.y;
    size_t e = ((size_t)blockIdx.x*256 + threadIdx.x)*4;
    float4 acc = {0.f, 0.f, 0.f, 0.f};
    for (int i = 0; i < k; ++i) {
        float w = tw[b*16 + i];
        int  idx = ti[b*16 + i];
        float4 t = *(const float4*)&table[(size_t)idx*EPE + e];
        acc.x += w*t.x; acc.y += w*t.y; acc.z += w*t.z; acc.w += w*t.w;
    }
    *(float4*)&out[(size_t)b*EPE + e] = acc;
}

// ======================================================================
// MFMA bf16 flash attention, bf16 inputs, paired q-tiles for balance.
// Block = 4 waves; block a handles q-tiles a and 15-a (17 k-iters total).
// ======================================================================
#define PADK 72

__global__ __launch_bounds__(256) void attn_mfma_kernel(
    const unsigned short* __restrict__ Q, const unsigned short* __restrict__ K,
    const unsigned short* __restrict__ V, float* __restrict__ O)
{
    int aa = blockIdx.x, hh = blockIdx.y, b = blockIdx.z;
    int tid  = threadIdx.x;
    int wave = tid >> 6, lane = tid & 63;
    int lr = lane & 15, lg = lane >> 4;

    __shared__ __align__(16) unsigned short Kt[64][PADK];
    __shared__ __align__(16) unsigned short Vt[64][PADK];   // Vt[d][kv]
    __shared__ __align__(16) unsigned short Pt[64][PADK];

    for (int ph = 0; ph < 2; ++ph) {
        int qt = ph ? (15 - aa) : aa;
        const unsigned short* Qrow =
            Q + ((size_t)b*Sn + (size_t)qt*64 + wave*16 + lr)*Dn + hh*64;
        short8 qf0 = *(const short8*)&Qrow[lg*8];
        short8 qf1 = *(const short8*)&Qrow[32 + lg*8];

        f32x4 o[4];
#pragma unroll
        for (int ct = 0; ct < 4; ++ct) o[ct] = (f32x4){0.f,0.f,0.f,0.f};
        float m[4]  = {-1e30f,-1e30f,-1e30f,-1e30f};
        float l[4]  = {0.f,0.f,0.f,0.f};

        for (int kt = 0; kt <= qt; ++kt) {
            __syncthreads();   // prior LDS reads done
            const unsigned short* Kb = K + ((size_t)b*Sn + (size_t)kt*64)*Dn + hh*64;
            const unsigned short* Vb = V + ((size_t)b*Sn + (size_t)kt*64)*Dn + hh*64;
            // ---- stage K[kv][d] (bf16 direct copy) ----
#pragma unroll
            for (int it2 = 0; it2 < 2; ++it2) {
                int idx = tid + it2*256;               // 0..511
                int kv = idx >> 3, d0 = (idx & 7)*8;
                *(short8*)&Kt[kv][d0] = *(const short8*)&Kb[(size_t)kv*Dn + d0];
            }
            // ---- stage V transposed: Vt[d][kv] ----
#pragma unroll
            for (int it2 = 0; it2 < 2; ++it2) {
                int idx = tid + it2*256;
                int kv = idx & 63, d0 = (idx >> 6)*8;
                short8 w = *(const short8*)&Vb[(size_t)kv*Dn + d0];
#pragma unroll
                for (int e = 0; e < 8; ++e) Vt[d0+e][kv] = (unsigned short)w[e];
            }
            __syncthreads();

            // ---- S = Q K^T ----
            f32x4 s[4];
#pragma unroll
            for (int ct = 0; ct < 4; ++ct) {
                s[ct] = (f32x4){0.f,0.f,0.f,0.f};
                short8 k0 = *(const short8*)&Kt[ct*16 + lr][lg*8];
                short8 k1 = *(const short8*)&Kt[ct*16 + lr][32 + lg*8];
                s[ct] = __builtin_amdgcn_mfma_f32_16x16x32_bf16(qf0, k0, s[ct], 0, 0, 0);
                s[ct] = __builtin_amdgcn_mfma_f32_16x16x32_bf16(qf1, k1, s[ct], 0, 0, 0);
            }

            float mx[4] = {-1e30f,-1e30f,-1e30f,-1e30f};
            int qg0 = qt*64 + wave*16 + lg*4;
#pragma unroll
            for (int ct = 0; ct < 4; ++ct) {
                int kvg = kt*64 + ct*16 + lr;
#pragma unroll
                for (int r = 0; r < 4; ++r) {
                    float v = s[ct][r] * 0.125f;
                    if (kt == qt && kvg > qg0 + r) v = -1e30f;
                    s[ct][r] = v;
                    mx[r] = fmaxf(mx[r], v);
                }
            }
#pragma unroll
            for (int r = 0; r < 4; ++r) {
                mx[r] = fmaxf(mx[r], __shfl_xor(mx[r], 1));
                mx[r] = fmaxf(mx[r], __shfl_xor(mx[r], 2));
                mx[r] = fmaxf(mx[r], __shfl_xor(mx[r], 4));
                mx[r] = fmaxf(mx[r], __shfl_xor(mx[r], 8));
            }

            float corr[4], ps[4] = {0.f,0.f,0.f,0.f};
#pragma unroll
            for (int r = 0; r < 4; ++r) {
                float mn = fmaxf(m[r], mx[r]);
                corr[r] = __expf(m[r] - mn);
                m[r] = mn;
            }
#pragma unroll
            for (int ct = 0; ct < 4; ++ct)
#pragma unroll
                for (int r = 0; r < 4; ++r) {
                    float e = __expf(s[ct][r] - m[r]);
                    s[ct][r] = e;
                    ps[r] += e;
                }
#pragma unroll
            for (int r = 0; r < 4; ++r) {
                ps[r] += __shfl_xor(ps[r], 1);
                ps[r] += __shfl_xor(ps[r], 2);
                ps[r] += __shfl_xor(ps[r], 4);
                ps[r] += __shfl_xor(ps[r], 8);
                l[r] = l[r]*corr[r] + ps[r];
#pragma unroll
                for (int ct = 0; ct < 4; ++ct) o[ct][r] *= corr[r];
            }

            // ---- P (D-layout) -> LDS bf16 ----
#pragma unroll
            for (int ct = 0; ct < 4; ++ct)
#pragma unroll
                for (int r = 0; r < 4; ++r)
                    Pt[wave*16 + lg*4 + r][ct*16 + lr] = f2bf(s[ct][r]);
            __syncthreads();

            short8 pa0 = *(const short8*)&Pt[wave*16 + lr][lg*8];
            short8 pa1 = *(const short8*)&Pt[wave*16 + lr][32 + lg*8];
#pragma unroll
            for (int ct = 0; ct < 4; ++ct) {
                short8 v0 = *(const short8*)&Vt[ct*16 + lr][lg*8];
                short8 v1 = *(const short8*)&Vt[ct*16 + lr][32 + lg*8];
                o[ct] = __builtin_amdgcn_mfma_f32_16x16x32_bf16(pa0, v0, o[ct], 0, 0, 0);
                o[ct] = __builtin_amdgcn_mfma_f32_16x16x32_bf16(pa1, v1, o[ct], 0, 0, 0);
            }
        }

        float* Op = O + ((size_t)b*Sn + (size_t)qt*64 + wave*16 + lg*4)*Dn + hh*64 + lr;
#pragma unroll
        for (int r = 0; r < 4; ++r) {
            float inv = 1.f / l[r];
#pragma unroll
            for (int ct = 0; ct < 4; ++ct)
                Op[(size_t)r*Dn + ct*16] = o[ct][r] * inv;
        }
    }
}

// ======================================================================
// Knowledge memory, wave-per-token. Top-16 via threshold + bitonic:
//   T = 16th largest of the 64 lane-maxima  (=> all true top-16 >= T)
//   ballot-compact candidates >= T to LDS, bitonic-sort (val desc, idx asc)
//   -> exact top-16; then f32 rescore, exact top-8, softmax, V gather-add.
// Wave-uniform fallback to iterative extraction if >64 candidates.
// ======================================================================
__global__ __launch_bounds__(256) void mem_topk_wave(
    const float* __restrict__ ksc,   // [4096][4096] chunk-local approx scores
    const float* __restrict__ hm,    // [8192][256] f32
    const float* __restrict__ kK,    // [4096][256]
    const float* __restrict__ kV,    // [4096][1024]
    float* __restrict__ out, int tok0)
{
    int wave = threadIdx.x >> 6, lane = threadIdx.x & 63;
    int t = blockIdx.x*4 + wave;            // chunk-local token
    const float* row = ksc + (size_t)t*NKn;

    // lane owns 64 contiguous scores; track local max while loading
    float v[64];
    float lmax = -3e38f;
#pragma unroll
    for (int j4 = 0; j4 < 16; ++j4) {
        float4 f = *(const float4*)&row[lane*64 + j4*4];
        v[j4*4+0]=f.x; v[j4*4+1]=f.y; v[j4*4+2]=f.z; v[j4*4+3]=f.w;
        lmax = fmaxf(lmax, fmaxf(fmaxf(f.x, f.y), fmaxf(f.z, f.w)));
    }

    // ---- bitonic sort of lane maxima (values only), descending ----
    float sv = lmax;
#pragma unroll
    for (int k = 2; k <= 64; k <<= 1) {
#pragma unroll
        for (int j = k >> 1; j >= 1; j >>= 1) {
            float ov = __shfl_xor(sv, j);
            bool keepLarger = (((lane & j) == 0) == ((lane & k) == 0));
            float mx = fmaxf(sv, ov), mn = fminf(sv, ov);
            sv = keepLarger ? mx : mn;
        }
    }
    float T = __shfl(sv, 15);   // 16th largest lane max

    __shared__ float s_cv[4][64];
    __shared__ int   s_cix[4][64];
    __shared__ float s_cs[4][16];
    __shared__ int   s_tix[4][16];

    // ---- ballot-compact candidates (v >= T) into LDS ----
    int base = 0;
#pragma unroll
    for (int j = 0; j < 64; ++j) {
        bool c = (v[j] >= T);
        unsigned long long msk = __ballot(c);
        if (c) {
            int pos = base + (int)__popcll(msk & ((1ull << lane) - 1ull));
            if (pos < 64) { s_cv[wave][pos] = v[j]; s_cix[wave][pos] = lane*64 + j; }
        }
        base += (int)__popcll(msk);
    }
    int C = base;     // wave-uniform

    if (C <= 64) {
        // ---- bitonic sort candidates by (value desc, index asc) ----
        float cv2 = (lane < C) ? s_cv[wave][lane] : -3e38f;
        int   cix = (lane < C) ? s_cix[wave][lane] : 0x7fffffff;
#pragma unroll
        for (int k = 2; k <= 64; k <<= 1) {
#pragma unroll
            for (int j = k >> 1; j >= 1; j >>= 1) {
                float ov = __shfl_xor(cv2, j);
                int   oi = __shfl_xor(cix, j);
                bool amLarger = (cv2 > ov) || (cv2 == ov && cix < oi);
                bool keepLarger = (((lane & j) == 0) == ((lane & k) == 0));
                if (amLarger != keepLarger) { cv2 = ov; cix = oi; }
            }
        }
        if (lane < 16) s_tix[wave][lane] = cix;
    } else {
        // ---- fallback: iterative extraction (exact, slow, ~never taken) ----
        for (int it = 0; it < 16; ++it) {
            float bv = -3e38f; int bi = 0x7fffffff;
#pragma unroll
            for (int j = 0; j < 64; ++j) {
                int n = lane*64 + j;
                if (v[j] > bv || (v[j] == bv && n < bi)) { bv = v[j]; bi = n; }
            }
#pragma unroll
            for (int off = 32; off >= 1; off >>= 1) {
                float ov = __shfl_xor(bv, off);
                int   oi = __shfl_xor(bi, off);
                if (ov > bv || (ov == bv && oi < bi)) { bv = ov; bi = oi; }
            }
            if (lane == 0) s_tix[wave][it] = bi;
#pragma unroll
            for (int j = 0; j < 64; ++j)
                if (lane*64 + j == bi) v[j] = -3e38f;
        }
    }

    // ---- f32 rescore: lane = cand*4 + quarter; 64 elems each ----
    int c = lane >> 2, q = lane & 3;
    int kidx = s_tix[wave][c];
    const float* kr = kK + (size_t)kidx*Rn;
    const float* hr = hm + (size_t)(tok0 + t)*Rn;
    float d = 0.f;
#pragma unroll
    for (int j4 = 0; j4 < 16; ++j4) {
        float4 a  = *(const float4*)&hr[q*64 + j4*4];
        float4 bb = *(const float4*)&kr[q*64 + j4*4];
        d += a.x*bb.x + a.y*bb.y + a.z*bb.z + a.w*bb.w;
    }
    d += __shfl_xor(d, 1);
    d += __shfl_xor(d, 2);
    if (q == 0) s_cs[wave][c] = d * 0.0625f;      // 1/sqrt(256)

    // ---- exact top-8 of 16 (in-wave; all lanes learn all winners) ----
    float cv = (lane < 16) ? s_cs[wave][lane] : -3e38f;
    int   ck = (lane < 16) ? s_tix[wave][lane] : 0x7fffffff;
    float sv8[8]; int si[8];
#pragma unroll
    for (int it = 0; it < 8; ++it) {
        float bv = cv; int bk = ck;
#pragma unroll
        for (int off = 32; off >= 1; off >>= 1) {
            float ov = __shfl_xor(bv, off);
            int   ok = __shfl_xor(bk, off);
            if (ov > bv || (ov == bv && ok < bk)) { bv = ov; bk = ok; }
        }
        sv8[it] = bv; si[it] = bk;
        if (ck == bk) cv = -3e38f;     // knowledge indices distinct
    }

    // ---- softmax over 8 + weighted V gather, add into out ----
    float mxv = sv8[0];
#pragma unroll
    for (int kx = 1; kx < 8; ++kx) mxv = fmaxf(mxv, sv8[kx]);
    float p[8]; float sum = 0.f;
#pragma unroll
    for (int kx = 0; kx < 8; ++kx) { p[kx] = __expf(sv8[kx] - mxv); sum += p[kx]; }
    float invs = 1.f / sum;
    float4 acc0 = {0,0,0,0}, acc1 = {0,0,0,0}, acc2 = {0,0,0,0}, acc3 = {0,0,0,0};
#pragma unroll
    for (int kx = 0; kx < 8; ++kx) {
        float pk = p[kx]*invs;
        const float* vp = kV + (size_t)si[kx]*Dn + lane*16;
        float4 v0 = *(const float4*)(vp + 0);
        float4 v1 = *(const float4*)(vp + 4);
        float4 v2 = *(const float4*)(vp + 8);
        float4 v3 = *(const float4*)(vp + 12);
        acc0.x += pk*v0.x; acc0.y += pk*v0.y; acc0.z += pk*v0.z; acc0.w += pk*v0.w;
        acc1.x += pk*v1.x; acc1.y += pk*v1.y; acc1.z += pk*v1.z; acc1.w += pk*v1.w;
        acc2.x += pk*v2.x; acc2.y += pk*v2.y; acc2.z += pk*v2.z; acc2.w += pk*v2.w;
        acc3.x += pk*v3.x; acc3.y += pk*v3.y; acc3.z += pk*v3.z; acc3.w += pk*v3.w;
    }
    float* op = out + (size_t)(tok0 + t)*Dn + lane*16;
    float4 c0 = *(const float4*)(op + 0);
    float4 c1 = *(const float4*)(op + 4);
    float4 c2 = *(const float4*)(op + 8);
    float4 c3 = *(const float4*)(op + 12);
    c0.x+=acc0.x; c0.y+=acc0.y; c0.z+=acc0.z; c0.w+=acc0.w;
    c1.x+=acc1.x; c1.y+=acc1.y; c1.z+=acc1.z; c1.w+=acc1.w;
    c2.x+=acc2.x; c2.y+=acc2.y; c2.z+=acc2.z; c2.w+=acc2.w;
    c3.x+=acc3.x; c3.y+=acc3.y; c3.z+=acc3.z; c3.w+=acc3.w;
    *(float4*)(op + 0)  = c0;
    *(float4*)(op + 4)  = c1;
    *(float4*)(op + 8)  = c2;
    *(float4*)(op + 12) = c3;
}

// ======================================================================
extern "C" void kernel_launch(void* const* d_in, const int* in_sizes, int n_in,
                              void* d_out, int out_size, void* d_ws, size_t ws_size,
                              hipStream_t stream)
{
    const float* x          = (const float*)d_in[0];
    const float* imp        = (const float*)d_in[1];
    const float* compress_w = (const float*)d_in[2];
    const float* expQ_w     = (const float*)d_in[3];
    const float* expK_w     = (const float*)d_in[4];
    const float* expV_w     = (const float*)d_in[5];
    const float* memory_w   = (const float*)d_in[6];
    const float* neurons    = (const float*)d_in[7];   // [64, D, R]
    const float* pool       = (const float*)d_in[8];   // [64, R, D]
    const float* kK         = (const float*)d_in[9];   // [4096, R]
    const float* kV         = (const float*)d_in[10];  // [4096, D]
    const float* Wo         = (const float*)d_in[11];  // [D, D]
    float* out = (float*)d_out;

    // ---- workspace layout (~150 MB) ----
    char* ws = (char*)d_ws;
    size_t off = 0;
    auto alloc = [&](size_t bytes) {
        size_t o = off; off = (off + bytes + 255) & ~(size_t)255; return (void*)(ws + o);
    };
    float* wcat    = (float*)alloc((size_t)5*64*Dn*4);     // concat router weights
    float* logits  = (float*)alloc((size_t)TOK*320*4);
    float* partial = (float*)alloc((size_t)40*4*64*4);
    float* tw      = (float*)alloc((size_t)5*Bn*16*4);
    int*   ti      = (int*)  alloc((size_t)5*Bn*16*4);
    float* sh_c = (float*)alloc((size_t)Bn*EPE*4);
    float* sh_m = (float*)alloc((size_t)Bn*EPE*4);
    float* sQ   = (float*)alloc((size_t)Bn*EPE*4);
    float* sK   = (float*)alloc((size_t)Bn*EPE*4);
    float* sV   = (float*)alloc((size_t)Bn*EPE*4);
    float* h    = (float*)alloc((size_t)Bn*Sn*Rn*4);
    float* hm   = (float*)alloc((size_t)Bn*Sn*Rn*4);
    unsigned short* Qb16 = (unsigned short*)alloc((size_t)Bn*Sn*Dn*2);
    unsigned short* Kb16 = (unsigned short*)alloc((size_t)Bn*Sn*Dn*2);
    unsigned short* Vb16 = (unsigned short*)alloc((size_t)Bn*Sn*Dn*2);
    float* Ob   = (float*)alloc((size_t)Bn*Sn*Dn*4);
    // ksc (64 MB per chunk) aliases Qb16..Ob (80 MB), all dead post-Wo
    float* ksc = (float*)Qb16;
    (void)ws_size; (void)in_sizes; (void)n_in; (void)out_size;

    // ---- 1. routers: concat weights, one split-bf16 GEMM, fused post ----
    hipMemcpyAsync(wcat + 0*64*Dn, compress_w, (size_t)64*Dn*4, hipMemcpyDeviceToDevice, stream);
    hipMemcpyAsync(wcat + 1*64*Dn, expQ_w,     (size_t)64*Dn*4, hipMemcpyDeviceToDevice, stream);
    hipMemcpyAsync(wcat + 2*64*Dn, expK_w,     (size_t)64*Dn*4, hipMemcpyDeviceToDevice, stream);
    hipMemcpyAsync(wcat + 3*64*Dn, expV_w,     (size_t)64*Dn*4, hipMemcpyDeviceToDevice, stream);
    hipMemcpyAsync(wcat + 4*64*Dn, memory_w,   (size_t)64*Dn*4, hipMemcpyDeviceToDevice, stream);
    bf16_gemm<<<dim3(5, 64, 1), 256, 0, stream>>>(
        x, wcat, logits, TOK, 320, Dn, 0LL, 0LL, 0LL, 1.f, 1, 1, 1, 0);
    router_post<<<160, 256, 0, stream>>>(logits, imp, partial);
    topk_router<<<40, 64, 0, stream>>>(partial, tw, ti);

    // ---- 2. expert combines (0=c,1=Q,2=K,3=V,4=mem) ----
    dim3 cgrid(EPE/1024, Bn);
    combine_kernel<<<cgrid, 256, 0, stream>>>(neurons, tw + 0*128, ti + 0*128, sh_c, 16);
    combine_kernel<<<cgrid, 256, 0, stream>>>(pool,    tw + 1*128, ti + 1*128, sQ,   8);
    combine_kernel<<<cgrid, 256, 0, stream>>>(pool,    tw + 2*128, ti + 2*128, sK,   8);
    combine_kernel<<<cgrid, 256, 0, stream>>>(pool,    tw + 3*128, ti + 3*128, sV,   8);
    combine_kernel<<<cgrid, 256, 0, stream>>>(neurons, tw + 4*128, ti + 4*128, sh_m, 16);

    // ---- 3. h = x @ sh_c ; hm = x @ sh_m  (split-bf16, f32-accurate) ----
    bf16_gemm<<<dim3(Rn/64, Sn/128, Bn), 256, 0, stream>>>(
        x, sh_c, h, Sn, Rn, Dn, (long long)Sn*Dn, (long long)EPE, (long long)Sn*Rn, 1.f, 0, 1, 1, 0);
    bf16_gemm<<<dim3(Rn/64, Sn/128, Bn), 256, 0, stream>>>(
        x, sh_m, hm, Sn, Rn, Dn, (long long)Sn*Dn, (long long)EPE, (long long)Sn*Rn, 1.f, 0, 1, 1, 0);

    // ---- 4. Q/K/V = h @ sharedX (split-bf16, bf16 output) ----
    bf16_gemm<<<dim3(Dn/64, Sn/128, Bn), 256, 0, stream>>>(
        h, sQ, (float*)Qb16, Sn, Dn, Rn, (long long)Sn*Rn, (long long)EPE, (long long)Sn*Dn, 1.f, 0, 1, 1, 1);
    bf16_gemm<<<dim3(Dn/64, Sn/128, Bn), 256, 0, stream>>>(
        h, sK, (float*)Kb16, Sn, Dn, Rn, (long long)Sn*Rn, (long long)EPE, (long long)Sn*Dn, 1.f, 0, 1, 1, 1);
    bf16_gemm<<<dim3(Dn/64, Sn/128, Bn), 256, 0, stream>>>(
        h, sV, (float*)Vb16, Sn, Dn, Rn, (long long)Sn*Rn, (long long)EPE, (long long)Sn*Dn, 1.f, 0, 1, 1, 1);

    // ---- 5. causal flash attention (bf16 in, paired q-tiles) ----
    attn_mfma_kernel<<<dim3(8, NHn, Bn), 256, 0, stream>>>(Qb16, Kb16, Vb16, Ob);

    // ---- 6. output projection: d_out = O @ Wo^T (split-A bf16) ----
    bf16_gemm<<<dim3(Dn/64, TOK/128, 1), 256, 0, stream>>>(
        Ob, Wo, out, TOK, Dn, Dn, 0LL, 0LL, 0LL, 1.f, 1, 1, 0, 0);

    // ---- 7. knowledge memory: 2 chunks of 4096 tokens ----
    for (int c = 0; c < 2; ++c) {
        bf16_gemm<<<dim3(NKn/64, 4096/128, 1), 256, 0, stream>>>(
            hm + (size_t)c*4096*Rn, kK, ksc, 4096, NKn, Rn, 0LL, 0LL, 0LL,
            0.0625f, 1, 0, 0, 0);
        mem_topk_wave<<<1024, 256, 0, stream>>>(ksc, hm, kK, kV, out, c*4096);
    }
}